// Round 9
// baseline (435.411 us; speedup 1.0000x reference)
//
#include <hip/hip_runtime.h>
#include <math.h>

typedef unsigned short u16;
typedef unsigned int u32;
typedef __attribute__((ext_vector_type(8))) short short8v;
typedef __attribute__((ext_vector_type(4))) float f32x4;

__device__ __forceinline__ u16 f2bf(float f) {
    u32 u = __float_as_uint(f);
    u32 r = (u + 0x7fffu + ((u >> 16) & 1u)) >> 16;
    return (u16)r;
}

// async global->LDS DMA, 16 B per lane; lds dst = wave-uniform base + lane*16
#define GLOAD_LDS(g, l)                                                        \
    __builtin_amdgcn_global_load_lds(                                          \
        (const __attribute__((address_space(1))) void*)(g),                    \
        (__attribute__((address_space(3))) void*)(l), 16, 0, 0)

#define SCHED_FENCE() __builtin_amdgcn_sched_barrier(0)

// log2(10000)/512
#define ROPE_LOG2C (13.287712379549449f / 512.0f)

// ================= fused prep kernel =================
__device__ __forceinline__ void cast_body(const float* __restrict__ x,
                                          u16* __restrict__ y, int L, int tid) {
    const int gid = L * 256 + tid;
    float4 v = ((const float4*)x)[gid];
    ushort4 o;
    o.x = f2bf(v.x); o.y = f2bf(v.y); o.z = f2bf(v.z); o.w = f2bf(v.w);
    ((ushort4*)y)[gid] = o;
}

__device__ __forceinline__ void tcast64_body(const float* __restrict__ S,
                                             u16* __restrict__ Dt, int K, int N,
                                             int n0, int k0, int tid,
                                             char* smem) {
    float (*tile)[65] = (float (*)[65])smem;
    const int tx = tid & 15, ty = tid >> 4;
#pragma unroll
    for (int i = 0; i < 4; i++) {
        const int kr = ty + 16 * i;
        const float4 v = *(const float4*)&S[(size_t)(k0 + kr) * N + n0 + tx * 4];
        tile[kr][tx * 4 + 0] = v.x;
        tile[kr][tx * 4 + 1] = v.y;
        tile[kr][tx * 4 + 2] = v.z;
        tile[kr][tx * 4 + 3] = v.w;
    }
    __syncthreads();
#pragma unroll
    for (int i = 0; i < 4; i++) {
        const int nr = ty + 16 * i;
        ushort4 o;
        o.x = f2bf(tile[tx * 4 + 0][nr]);
        o.y = f2bf(tile[tx * 4 + 1][nr]);
        o.z = f2bf(tile[tx * 4 + 2][nr]);
        o.w = f2bf(tile[tx * 4 + 3][nr]);
        *(ushort4*)&Dt[(size_t)(n0 + nr) * K + k0 + tx * 4] = o;
    }
}

__device__ __forceinline__ void rope1_body(const float* __restrict__ A,
                                           float* __restrict__ P, int blk,
                                           int tid, char* smem) {
    float (*sc)[17]  = (float (*)[17])(smem);
    float (*cc)[17]  = (float (*)[17])(smem + 1088);
    float (*Als)[17] = (float (*)[17])(smem + 2176);
    float (*Alc)[17] = (float (*)[17])(smem + 3264);
    const int tt = tid >> 4, rr = tid & 15;
    const int t = blk * 16 + tt;
    float acc = 0.f;
    for (int i0 = 0; i0 < 512; i0 += 16) {
        __syncthreads();
        {
            const int i = i0 + rr;
            const float th = exp2f(-(float)i * ROPE_LOG2C);
            const float ang = (float)t * th;
            sc[tt][rr] = sinf(ang);
            cc[tt][rr] = cosf(ang);
            Als[tt][rr] = A[(i0 + tt) * 16 + rr];
            Alc[tt][rr] = A[(512 + i0 + tt) * 16 + rr];
        }
        __syncthreads();
#pragma unroll
        for (int ii = 0; ii < 16; ++ii)
            acc = fmaf(sc[tt][ii], Als[ii][rr],
                       fmaf(cc[tt][ii], Alc[ii][rr], acc));
    }
    P[t * 16 + rr] = acc;
}

__global__ __launch_bounds__(256) void prep_k(
    const float* __restrict__ tgt, u16* __restrict__ tgtb,
    const float* __restrict__ Wq, u16* __restrict__ Wqt,
    const float* __restrict__ Wk, u16* __restrict__ Wkt,
    const float* __restrict__ Wv, u16* __restrict__ Wvt,
    const float* __restrict__ Wo, u16* __restrict__ Wot,
    const float* __restrict__ W1, u16* __restrict__ W1t,
    const float* __restrict__ W2, u16* __restrict__ W2t,
    const float* __restrict__ rA, float* __restrict__ Pp) {
    __shared__ char smem[64 * 65 * 4];
    const int L = blockIdx.x, tid = threadIdx.x;
    if (L < 128) {                                     // rope pass 1 (longest)
        rope1_body(rA, Pp, L, tid, smem);
    } else if (L < 4224) {                             // cast tgt -> bf16
        cast_body(tgt, tgtb, L - 128, tid);
    } else if (L < 5248) {                             // 4x 1024^2 transpose
        const int i = L - 4224;
        const int r = i >> 8, j = i & 255;
        const float* S = r == 0 ? Wq : (r == 1 ? Wk : (r == 2 ? Wv : Wo));
        u16* Dt = r == 0 ? Wqt : (r == 1 ? Wkt : (r == 2 ? Wvt : Wot));
        tcast64_body(S, Dt, 1024, 1024, (j & 15) * 64, (j >> 4) * 64, tid, smem);
    } else if (L < 6272) {                             // W1 (1024x4096)
        const int j = L - 5248;
        tcast64_body(W1, W1t, 1024, 4096, (j & 63) * 64, (j >> 6) * 64, tid, smem);
    } else {                                           // W2 (4096x1024)
        const int j = L - 6272;
        tcast64_body(W2, W2t, 4096, 1024, (j & 15) * 64, (j >> 4) * 64, tid, smem);
    }
}

// ---------- V transpose per head: vv[m][h*64+d] -> Vt[bh][d][key] ----------
__global__ __launch_bounds__(256) void vtrans_k(const u16* __restrict__ vv,
                                                u16* __restrict__ Vt) {
    __shared__ u16 tile[32][33];
    const int key0 = blockIdx.x * 32, d0 = blockIdx.y * 32, bh = blockIdx.z;
    const int b = bh >> 4, h = bh & 15;
    const int tx = threadIdx.x & 31, ty = threadIdx.x >> 5;
#pragma unroll
    for (int i = 0; i < 4; i++)
        tile[ty + 8 * i][tx] =
            vv[(size_t)(b * 2048 + key0 + ty + 8 * i) * 1024 + h * 64 + d0 + tx];
    __syncthreads();
#pragma unroll
    for (int i = 0; i < 4; i++) {
        const int d = d0 + ty + 8 * i;
        const int key = key0 + tx;
        const int ksw = (key & ~63) | ((((key >> 3) & 7) ^ (d & 7)) << 3) | (key & 7);
        Vt[((size_t)bh * 64 + d) * 2048 + ksw] = tile[tx][ty + 8 * i];
    }
}

// ---------- RoPE pass 2 ----------
__global__ void rope2_k(const float* __restrict__ P, const float* __restrict__ Bw,
                        float* __restrict__ sf, float* __restrict__ cf) {
    const int gid = blockIdx.x * blockDim.x + threadIdx.x;
    if (gid >= 2048 * 512) return;
    const int t = gid >> 9, i = gid & 511;
    float ls = 0.f, lc = 0.f;
#pragma unroll
    for (int r = 0; r < 16; ++r) {
        const float p = P[t * 16 + r];
        ls = fmaf(p, Bw[r * 1024 + i], ls);
        lc = fmaf(p, Bw[r * 1024 + 512 + i], lc);
    }
    const float th = exp2f(-(float)i * ROPE_LOG2C);
    const float ang = (float)t * th;
    sf[gid] = sinf(ang) + ls;
    cf[gid] = cosf(ang) + lc;
}

// XCD supertile mapping: linear grid; xcd = L&7 owns an rn x rm tile region.
__device__ __forceinline__ void xcd_tile(int L, int xn, int rn, int rm,
                                         int& tm, int& tn) {
    const int xcd = L & 7, i = L >> 3;
    const int cx = xcd % xn, cy = xcd / xn;
    tn = cx * rn + (i % rn);
    tm = cy * rm + (i / rn);
}

// ---------- MFMA GEMM (128xBN, 4 waves): 3-stage DMA pipeline ----
// Split-K: tm >= mtiles selects K-half kh=1 (A/Bt advance kh*K columns;
// fp32 partial written to Cp2). lda/ldb are full row strides.
enum { EP_NONE = 0, EP_RELU = 3, EP_PART = 4 };

template <int EPI, bool CBF, int BN>
__global__ __launch_bounds__(256) void mgemm_k(
    const u16* __restrict__ A, const u16* __restrict__ Bt,
    const float* __restrict__ bias, void* __restrict__ Cp,
    void* __restrict__ Cp2, int M, int N, int K, int lda, int ldb,
    int xn, int rn, int rm, int mtiles) {
    constexpr int NT = BN / 32;            // n-frags per wave
    __shared__ u16 As[3 * 128 * 32];
    __shared__ u16 Bs[3 * BN * 32];
    const int tid = threadIdx.x;
    const int w = tid >> 6, l = tid & 63;
    const int quad = l >> 4, lr = l & 15;
    const int wr = w >> 1, wc = w & 1;
    int tm, tn;
    xcd_tile(blockIdx.x, xn, rn, rm, tm, tn);
    int kh = 0;
    if (tm >= mtiles) { kh = 1; tm -= mtiles; }
    const u16* Ak = A + (size_t)kh * K;
    const u16* Bk = Bt + (size_t)kh * K;
    void* Co = kh ? Cp2 : Cp;
    const int m0 = tm * 128, n0 = tn * BN;

    const int srow = w * 16 + (l >> 2);    // staging row (64-row round)
    const int scol = (((l & 3) ^ ((l >> 3) & 3)) * 8);
    const u16* ag0 = Ak + (size_t)(m0 + srow) * lda + scol;
    const u16* ag1 = Ak + (size_t)(m0 + 64 + srow) * lda + scol;
    const u16* bg0 = Bk + (size_t)(n0 + srow) * ldb + scol;
    const u16* bg1 = Bk + (size_t)(n0 + 64 + srow) * ldb + scol;  // BN==128 only

    f32x4 acc[4][NT];
#pragma unroll
    for (int i = 0; i < 4; i++)
#pragma unroll
        for (int j = 0; j < NT; j++) acc[i][j] = (f32x4)(0.0f);

    // prologue: stage tiles 0,1 into buffers 0,1 (issue order = tile order)
    {
        GLOAD_LDS(ag0, As + w * 512);
        GLOAD_LDS(ag1, As + 2048 + w * 512);
        GLOAD_LDS(bg0, Bs + w * 512);
        if (BN == 128) GLOAD_LDS(bg1, Bs + 2048 + w * 512);
        GLOAD_LDS(ag0 + 32, As + 4096 + w * 512);
        GLOAD_LDS(ag1 + 32, As + 4096 + 2048 + w * 512);
        GLOAD_LDS(bg0 + 32, Bs + BN * 32 + w * 512);
        if (BN == 128) GLOAD_LDS(bg1 + 32, Bs + BN * 32 + 2048 + w * 512);
    }

    const int niter = K >> 5;
    const int xsw = ((lr >> 1) & 3) << 3;  // read-side granule XOR (u16 units)
    int bc = 0, bs = 2;                    // compute buf, stage buf (i+2)%3
    for (int i = 0; i < niter; ++i) {
        SCHED_FENCE();
        if (i + 1 < niter) {
            if (BN == 128) asm volatile("s_waitcnt vmcnt(4) lgkmcnt(0)" ::: "memory");
            else           asm volatile("s_waitcnt vmcnt(3) lgkmcnt(0)" ::: "memory");
        } else {
            asm volatile("s_waitcnt vmcnt(0) lgkmcnt(0)" ::: "memory");
        }
        __builtin_amdgcn_s_barrier();
        SCHED_FENCE();
        if (i + 2 < niter) {
            const int kk = (i + 2) << 5;
            u16* Ab = As + bs * 4096;
            u16* Bb = Bs + bs * (BN * 32);
            GLOAD_LDS(ag0 + kk, Ab + w * 512);
            GLOAD_LDS(ag1 + kk, Ab + 2048 + w * 512);
            GLOAD_LDS(bg0 + kk, Bb + w * 512);
            if (BN == 128) GLOAD_LDS(bg1 + kk, Bb + 2048 + w * 512);
        }
        const u16* Ac = As + bc * 4096;
        const u16* Bc = Bs + bc * (BN * 32);
        short8v af[4], bf[NT];
#pragma unroll
        for (int mt = 0; mt < 4; ++mt)
            af[mt] = *(const short8v*)&Ac[(wr * 64 + mt * 16 + lr) * 32 +
                                          ((quad << 3) ^ xsw)];
#pragma unroll
        for (int nt = 0; nt < NT; ++nt)
            bf[nt] = *(const short8v*)&Bc[(wc * (BN / 2) + nt * 16 + lr) * 32 +
                                          ((quad << 3) ^ xsw)];
#pragma unroll
        for (int mt = 0; mt < 4; ++mt)
#pragma unroll
            for (int nt = 0; nt < NT; ++nt)
                acc[mt][nt] = __builtin_amdgcn_mfma_f32_16x16x32_bf16(
                    af[mt], bf[nt], acc[mt][nt], 0, 0, 0);
        bc = (bc == 2) ? 0 : bc + 1;
        bs = (bs == 2) ? 0 : bs + 1;
    }

#pragma unroll
    for (int mt = 0; mt < 4; ++mt) {
#pragma unroll
        for (int nt = 0; nt < NT; ++nt) {
            const int n = n0 + wc * (BN / 2) + nt * 16 + lr;
            const float bb = (EPI == EP_PART) ? 0.0f : bias[n];
#pragma unroll
            for (int reg = 0; reg < 4; ++reg) {
                const int m = m0 + wr * 64 + mt * 16 + quad * 4 + reg;
                float v = acc[mt][nt][reg] + bb;
                if (EPI == EP_RELU) v = fmaxf(v, 0.f);
                if (CBF) ((u16*)Co)[(size_t)m * N + n] = f2bf(v);
                else     ((float*)Co)[(size_t)m * N + n] = v;
            }
        }
    }
}

// ---------- merged QKV GEMM (N=3072), BN=64, 3-stage pipeline, RoPE ----
// 48n x 32m 128x64 tiles = 1536 blocks (4 resident/CU at 36 KB LDS).
__global__ __launch_bounds__(256) void mqkv_k(
    const u16* __restrict__ A, const u16* __restrict__ Bt,
    const float* __restrict__ bq, const float* __restrict__ bk,
    const float* __restrict__ bv, const float* __restrict__ sf,
    const float* __restrict__ cf, u16* __restrict__ out) {
    const int K = 1024;
    __shared__ u16 As[3 * 128 * 32];
    __shared__ u16 Bs[3 * 64 * 32];
    const int tid = threadIdx.x;
    const int w = tid >> 6, l = tid & 63;
    const int quad = l >> 4, lr = l & 15;
    const int wr = w >> 1, wc = w & 1;
    int tm, tn;
    xcd_tile(blockIdx.x, 4, 12, 16, tm, tn);   // 48n x 32m grid
    const int m0 = tm * 128, n0 = tn * 64;

    const int srow = w * 16 + (l >> 2);
    const int scol = (((l & 3) ^ ((l >> 3) & 3)) * 8);
    const u16* ag0 = A + (size_t)(m0 + srow) * K + scol;
    const u16* ag1 = A + (size_t)(m0 + 64 + srow) * K + scol;
    const u16* bg0 = Bt + (size_t)(n0 + srow) * K + scol;

    f32x4 acc[4][2];
#pragma unroll
    for (int i = 0; i < 4; i++)
#pragma unroll
        for (int j = 0; j < 2; j++) acc[i][j] = (f32x4)(0.0f);

    // prologue: tiles 0,1 (3 loads each, issue order = tile order)
    {
        GLOAD_LDS(ag0, As + w * 512);
        GLOAD_LDS(ag1, As + 2048 + w * 512);
        GLOAD_LDS(bg0, Bs + w * 512);
        GLOAD_LDS(ag0 + 32, As + 4096 + w * 512);
        GLOAD_LDS(ag1 + 32, As + 4096 + 2048 + w * 512);
        GLOAD_LDS(bg0 + 32, Bs + 2048 + w * 512);
    }
    const int xsw = ((lr >> 1) & 3) << 3;
    int bc = 0, bsb = 2;
    for (int i = 0; i < 32; ++i) {
        SCHED_FENCE();
        if (i + 1 < 32) {
            asm volatile("s_waitcnt vmcnt(3) lgkmcnt(0)" ::: "memory");
        } else {
            asm volatile("s_waitcnt vmcnt(0) lgkmcnt(0)" ::: "memory");
        }
        __builtin_amdgcn_s_barrier();
        SCHED_FENCE();
        if (i + 2 < 32) {
            const int kk = (i + 2) << 5;
            u16* Ab = As + bsb * 4096;
            u16* Bb = Bs + bsb * 2048;
            GLOAD_LDS(ag0 + kk, Ab + w * 512);
            GLOAD_LDS(ag1 + kk, Ab + 2048 + w * 512);
            GLOAD_LDS(bg0 + kk, Bb + w * 512);
        }
        const u16* Ac = As + bc * 4096;
        const u16* Bc = Bs + bc * 2048;
        short8v af[4], bf[2];
#pragma unroll
        for (int mt = 0; mt < 4; ++mt)
            af[mt] = *(const short8v*)&Ac[(wr * 64 + mt * 16 + lr) * 32 +
                                          ((quad << 3) ^ xsw)];
#pragma unroll
        for (int nt = 0; nt < 2; ++nt)
            bf[nt] = *(const short8v*)&Bc[(wc * 32 + nt * 16 + lr) * 32 +
                                          ((quad << 3) ^ xsw)];
#pragma unroll
        for (int mt = 0; mt < 4; ++mt)
#pragma unroll
            for (int nt = 0; nt < 2; ++nt)
                acc[mt][nt] = __builtin_amdgcn_mfma_f32_16x16x32_bf16(
                    af[mt], bf[nt], acc[mt][nt], 0, 0, 0);
        bc = (bc == 2) ? 0 : bc + 1;
        bsb = (bsb == 2) ? 0 : bsb + 1;
    }

    const int which = n0 >> 10;  // block-uniform (64-tile within 1024 band)
    const float* bias = which == 0 ? bq : (which == 1 ? bk : bv);
    const bool doRope = which < 2;
    u16* Cp = out + (size_t)which * 4096 * 1024;

#pragma unroll
    for (int mt = 0; mt < 4; ++mt) {
#pragma unroll
        for (int nt = 0; nt < 2; ++nt) {
            const int n = n0 + wc * 32 + nt * 16 + lr;
            const int col = n & 1023;
            const float bb = bias[col];
#pragma unroll
            for (int reg = 0; reg < 4; ++reg) {
                const int m = m0 + wr * 64 + mt * 16 + quad * 4 + reg;
                float v = acc[mt][nt][reg] + bb;
                const float partner = __shfl_xor(v, 1);
                int colw = col;
                if (doRope) {
                    const int t = m & 2047;
                    const int fi = col >> 1;
                    const float svv = sf[t * 512 + fi];
                    const float cvv = cf[t * 512 + fi];
                    v = (col & 1) ? fmaf(partner, svv, v * cvv)
                                  : fmaf(v, cvv, -partner * svv);
                    if (which == 0) v *= 0.125f;
                    colw = (col & ~63) | ((((col >> 3) & 7) ^ (m & 7)) << 3) |
                           (col & 7);
                }
                Cp[(size_t)m * 1024 + colw] = f2bf(v);
            }
        }
    }
}

// ---------- MFMA flash attention v2 ----------
// 512 blocks, 4 waves, 128 q-rows/block (32/wave), KVBLK=64 double-buffered.
__global__ __launch_bounds__(256, 3) void mattn_k(
    const u16* __restrict__ Q, const u16* __restrict__ Kg,
    const u16* __restrict__ Vt, u16* __restrict__ O) {
    __shared__ u16 QPs[128 * 64];     // Q staging (prologue), then P tiles
    __shared__ u16 Ks[2][64 * 64];
    __shared__ u16 Vs[2][64 * 64];
    const int tid = threadIdx.x;
    const int w = tid >> 6, l = tid & 63;
    const int quad = l >> 4, lr = l & 15;
    const int L = blockIdx.x;                      // 512 blocks
    const int bh = (L & 7) * 4 + ((L >> 3) & 3);   // 4 bh per XCD (L2 locality)
    const int b = bh >> 4, h = bh & 15;
    const int row0 = (L >> 5) * 128;
    const size_t base = (size_t)b * 2048 * 1024 + (size_t)h * 64;
    const size_t vbase = (size_t)bh * 64 * 2048;

    const int dr = l >> 3;
    const int dc = (l & 7) * 8;
    const int g0 = w * 2, g1 = g0 + 1;
    const u16* kg0 = Kg + base + (size_t)(g0 * 8 + dr) * 1024 + dc;
    const u16* kg1 = Kg + base + (size_t)(g1 * 8 + dr) * 1024 + dc;
    const u16* vg0 = Vt + vbase + (size_t)(g0 * 8 + dr) * 2048 + dc;
    const u16* vg1 = Vt + vbase + (size_t)(g1 * 8 + dr) * 2048 + dc;

#pragma unroll
    for (int j = 0; j < 4; ++j) {
        const int g = w * 4 + j;
        GLOAD_LDS(Q + base + (size_t)(row0 + g * 8 + dr) * 1024 + dc,
                  QPs + g * 512);
    }
    GLOAD_LDS(kg0, Ks[0] + g0 * 512);
    GLOAD_LDS(kg1, Ks[0] + g1 * 512);
    GLOAD_LDS(vg0, Vs[0] + g0 * 512);
    GLOAD_LDS(vg1, Vs[0] + g1 * 512);
    __syncthreads();

    const int rsw = lr & 7;
    short8v qf[2][2];
#pragma unroll
    for (int ntq = 0; ntq < 2; ++ntq) {
        const int qr = w * 32 + ntq * 16 + lr;
#pragma unroll
        for (int kh = 0; kh < 2; ++kh)
            qf[ntq][kh] = *(const short8v*)&QPs[qr * 64 +
                (((kh * 4 + quad) ^ rsw) << 3)];
    }

    f32x4 o_acc[2][4];
#pragma unroll
    for (int i = 0; i < 2; ++i)
#pragma unroll
        for (int j = 0; j < 4; ++j) o_acc[i][j] = (f32x4)(0.0f);
    float lsum[2] = {0.f, 0.f};

    for (int i = 0; i < 32; ++i) {
        __syncthreads();
        if (i + 1 < 32) {
            const size_t kro = (size_t)((i + 1) << 6) * 1024;
            const int kco = (i + 1) << 6;
            u16* Kb = Ks[(i + 1) & 1];
            u16* Vb = Vs[(i + 1) & 1];
            GLOAD_LDS(kg0 + kro, Kb + g0 * 512);
            GLOAD_LDS(kg1 + kro, Kb + g1 * 512);
            GLOAD_LDS(vg0 + kco, Vb + g0 * 512);
            GLOAD_LDS(vg1 + kco, Vb + g1 * 512);
        }
        const u16* Kc = Ks[i & 1];
        const u16* Vc = Vs[i & 1];

        f32x4 s[4][2];
#pragma unroll
        for (int mt = 0; mt < 4; ++mt)
#pragma unroll
            for (int ntq = 0; ntq < 2; ++ntq) s[mt][ntq] = (f32x4)(0.0f);
#pragma unroll
        for (int mt = 0; mt < 4; ++mt) {
            const int kr = mt * 16 + lr;
            const short8v kf0 = *(const short8v*)&Kc[kr * 64 + ((quad ^ rsw) << 3)];
            const short8v kf1 = *(const short8v*)&Kc[kr * 64 + (((quad + 4) ^ rsw) << 3)];
#pragma unroll
            for (int ntq = 0; ntq < 2; ++ntq) {
                s[mt][ntq] = __builtin_amdgcn_mfma_f32_16x16x32_bf16(
                    kf0, qf[ntq][0], s[mt][ntq], 0, 0, 0);
                s[mt][ntq] = __builtin_amdgcn_mfma_f32_16x16x32_bf16(
                    kf1, qf[ntq][1], s[mt][ntq], 0, 0, 0);
            }
        }

#pragma unroll
        for (int ntq = 0; ntq < 2; ++ntq) {
            const int prow = w * 32 + ntq * 16 + lr;
#pragma unroll
            for (int mt = 0; mt < 4; ++mt) {
                const float e0 = __expf(s[mt][ntq][0]);
                const float e1 = __expf(s[mt][ntq][1]);
                const float e2 = __expf(s[mt][ntq][2]);
                const float e3 = __expf(s[mt][ntq][3]);
                lsum[ntq] += (e0 + e1) + (e2 + e3);
                u32 p01, p23;
                asm("v_cvt_pk_bf16_f32 %0, %1, %2" : "=v"(p01) : "v"(e0), "v"(e1));
                asm("v_cvt_pk_bf16_f32 %0, %1, %2" : "=v"(p23) : "v"(e2), "v"(e3));
                uint2 pv; pv.x = p01; pv.y = p23;
                *(uint2*)&QPs[prow * 64 +
                              (((mt * 2 + (quad >> 1)) ^ rsw) << 3) +
                              (quad & 1) * 4] = pv;
            }
        }

        short8v vf[4][2];
#pragma unroll
        for (int ntd = 0; ntd < 4; ++ntd) {
            const int vr = ntd * 16 + lr;
            vf[ntd][0] = *(const short8v*)&Vc[vr * 64 + ((quad ^ rsw) << 3)];
            vf[ntd][1] = *(const short8v*)&Vc[vr * 64 + (((quad + 4) ^ rsw) << 3)];
        }
        short8v pf[2][2];
#pragma unroll
        for (int mtq = 0; mtq < 2; ++mtq) {
            const int prow = w * 32 + mtq * 16 + lr;
            pf[mtq][0] = *(const short8v*)&QPs[prow * 64 + ((quad ^ rsw) << 3)];
            pf[mtq][1] = *(const short8v*)&QPs[prow * 64 + (((quad + 4) ^ rsw) << 3)];
        }
#pragma unroll
        for (int mtq = 0; mtq < 2; ++mtq)
#pragma unroll
            for (int ntd = 0; ntd < 4; ++ntd) {
                o_acc[mtq][ntd] = __builtin_amdgcn_mfma_f32_16x16x32_bf16(
                    pf[mtq][0], vf[ntd][0], o_acc[mtq][ntd], 0, 0, 0);
                o_acc[mtq][ntd] = __builtin_amdgcn_mfma_f32_16x16x32_bf16(
                    pf[mtq][1], vf[ntd][1], o_acc[mtq][ntd], 0, 0, 0);
            }
    }

    float rden[2];
#pragma unroll
    for (int ntq = 0; ntq < 2; ++ntq) {
        float t = lsum[ntq];
        t += __shfl_xor(t, 16);
        t += __shfl_xor(t, 32);
        rden[ntq] = 1.0f / t;
    }
#pragma unroll
    for (int mtq = 0; mtq < 2; ++mtq) {
#pragma unroll
        for (int reg = 0; reg < 4; ++reg) {
            const float dsc = __shfl(rden[mtq], quad * 4 + reg);
            const int m = row0 + w * 32 + mtq * 16 + quad * 4 + reg;
#pragma unroll
            for (int ntd = 0; ntd < 4; ++ntd)
                O[base + (size_t)m * 1024 + ntd * 16 + lr] =
                    f2bf(o_acc[mtq][ntd][reg] * dsc);
        }
    }
}

// ---------- fused partial-sum + bias + layernorm over 1024 cols ----------
__global__ __launch_bounds__(256) void lnf_k(
    const float* __restrict__ X, const float* __restrict__ P0,
    const float* __restrict__ P1, const float* __restrict__ cb,
    const float* __restrict__ g, const float* __restrict__ bb,
    float* __restrict__ outf, u16* __restrict__ outb) {
    const int row = blockIdx.x, tid = threadIdx.x;
    const size_t off = (size_t)row * 1024 + tid * 4;
    float4 xv = *(const float4*)&X[off];
    float4 p0 = *(const float4*)&P0[off];
    float4 p1 = *(const float4*)&P1[off];
    float4 c4 = *(const float4*)&cb[tid * 4];
    xv.x += p0.x + p1.x + c4.x;
    xv.y += p0.y + p1.y + c4.y;
    xv.z += p0.z + p1.z + c4.z;
    xv.w += p0.w + p1.w + c4.w;
    float s = xv.x + xv.y + xv.z + xv.w;
    float s2 = xv.x * xv.x + xv.y * xv.y + xv.z * xv.z + xv.w * xv.w;
#pragma unroll
    for (int msk = 32; msk >= 1; msk >>= 1) {
        s += __shfl_xor(s, msk);
        s2 += __shfl_xor(s2, msk);
    }
    __shared__ float red[8];
    const int wv = tid >> 6;
    if ((tid & 63) == 0) { red[wv] = s; red[wv + 4] = s2; }
    __syncthreads();
    s = red[0] + red[1] + red[2] + red[3];
    s2 = red[4] + red[5] + red[6] + red[7];
    const float mu = s * (1.f / 1024.f);
    float var = s2 * (1.f / 1024.f) - mu * mu;
    var = fmaxf(var, 0.f);
    const float rstd = rsqrtf(var + 1e-5f);
    float4 g4 = *(const float4*)&g[tid * 4];
    float4 b4 = *(const float4*)&bb[tid * 4];
    float o0 = (xv.x - mu) * rstd * g4.x + b4.x;
    float o1 = (xv.y - mu) * rstd * g4.y + b4.y;
    float o2 = (xv.z - mu) * rstd * g4.z + b4.z;
    float o3 = (xv.w - mu) * rstd * g4.w + b4.w;
    if (outf)
        *(float4*)(outf + off) = make_float4(o0, o1, o2, o3);
    if (outb) {
        ushort4 ov;
        ov.x = f2bf(o0); ov.y = f2bf(o1); ov.z = f2bf(o2); ov.w = f2bf(o3);
        *(ushort4*)(outb + off) = ov;
    }
}

extern "C" void kernel_launch(void* const* d_in, const int* in_sizes, int n_in,
                              void* d_out, int out_size, void* d_ws, size_t ws_size,
                              hipStream_t stream) {
    const float* tgt = (const float*)d_in[0];
    const float* Wq  = (const float*)d_in[1];
    const float* bq  = (const float*)d_in[2];
    const float* Wk  = (const float*)d_in[3];
    const float* bk  = (const float*)d_in[4];
    const float* Wv  = (const float*)d_in[5];
    const float* bv  = (const float*)d_in[6];
    const float* Wo  = (const float*)d_in[7];
    const float* bo  = (const float*)d_in[8];
    const float* W1  = (const float*)d_in[9];
    const float* b1  = (const float*)d_in[10];
    const float* W2  = (const float*)d_in[11];
    const float* b2  = (const float*)d_in[12];
    const float* g1  = (const float*)d_in[13];
    const float* be1 = (const float*)d_in[14];
    const float* g2  = (const float*)d_in[15];
    const float* be2 = (const float*)d_in[16];
    const float* rA  = (const float*)d_in[17];
    const float* rB  = (const float*)d_in[18];

    const int M = 4096, D = 1024, DFF = 4096;
    const size_t MD = (size_t)M * D;
    const size_t MB = 1u << 20;
    char* wsb = (char*)d_ws;

    // Lifetime-aliased layout (88 MB total):
    // [0,16)  Pp(tmp) -> q,kk (mqkv->mattn) -> PW0 (Wo->lnf1) -> h[0,16)
    // [16,24) vv (mqkv->vtrans) -> ctx (mattn->Wo) -> h[16,24)
    // [24,32) Vt (vtrans->mattn) -> h[24,32)
    // [32,48) sfp,cfp + tgtb (->mqkv) -> PW1 (Wo->lnf1) -> PF1 (FFN2->lnf2)
    // [48,64) x1 fp32 (lnf1->lnf2)
    // [64,72) Wqt..Wot (->mqkv/Wo) -> x1b (lnf1->FFN1) -> PF0 lo
    // [72,80) W1t (->FFN1) -> PF0 hi
    // [80,88) W2t (->FFN2)
    u16* q    = (u16*)wsb;
    u16* vv   = q + 2 * MD;
    u16* ctx  = (u16*)(wsb + 16 * MB);
    u16* Vt   = (u16*)(wsb + 24 * MB);
    u16* h    = q;
    float* PW0 = (float*)wsb;
    float* PW1 = (float*)(wsb + 32 * MB);
    float* PF0 = (float*)(wsb + 64 * MB);
    float* PF1 = (float*)(wsb + 32 * MB);
    float* sfp = (float*)(wsb + 32 * MB);
    float* cfp = sfp + (size_t)2048 * 512;
    u16* tgtb = (u16*)(wsb + 40 * MB);
    float* x1  = (float*)(wsb + 48 * MB);
    u16* x1b  = (u16*)(wsb + 64 * MB);
    u16* Wqt  = (u16*)(wsb + 64 * MB);
    u16* Wkt  = (u16*)(wsb + 66 * MB);
    u16* Wvt  = (u16*)(wsb + 68 * MB);
    u16* Wot  = (u16*)(wsb + 70 * MB);
    u16* W1t  = (u16*)(wsb + 72 * MB);
    u16* W2t  = (u16*)(wsb + 80 * MB);
    float* Pp = (float*)wsb;               // 128 KB, dead before mqkv

    // fused prep: rope1 + cast + 6 weight transposes (one launch)
    prep_k<<<dim3(7296), dim3(256), 0, stream>>>(
        tgt, tgtb, Wq, Wqt, Wk, Wkt, Wv, Wvt, Wo, Wot,
        W1, W1t, W2, W2t, rA, Pp);
    rope2_k<<<dim3(4096), dim3(256), 0, stream>>>(Pp, rB, sfp, cfp);

    // QKV BN=64: 48n x 32m = 1536 blocks (4 resident/CU); xn=4 -> 12n x 16m/XCD
    mqkv_k<<<dim3(1536), dim3(256), 0, stream>>>(
        tgtb, Wqt, bq, bk, bv, sfp, cfp, q);

    vtrans_k<<<dim3(64, 2, 32), dim3(256), 0, stream>>>(vv, Vt);

    // 512 blocks: 8 xcd x 4 bh x 16 row-tiles (128 q rows each)
    mattn_k<<<dim3(512), dim3(256), 0, stream>>>(q, q + MD, Vt, ctx);

    // Wo split-K x2, BN=128 (R6 best): 8n x (32m x 2kh) = 512 blocks, K=512
    mgemm_k<EP_PART, false, 128><<<dim3(512), dim3(256), 0, stream>>>(
        ctx, Wot, nullptr, PW0, PW1, M, D, 512, D, D, 1, 8, 8, 32);
    // lnf1: x_attn = tgt + PW0 + PW1 + bo -> LN -> x1 (fp32) + x1b (bf16)
    lnf_k<<<dim3(4096), dim3(256), 0, stream>>>(
        tgt, PW0, PW1, bo, g1, be1, x1, x1b);
    // FFN1: BN=128 -> 32n x 32m = 1024 blocks (4/CU); xn=4 -> 8n x 16m per XCD
    mgemm_k<EP_RELU, true, 128><<<dim3(1024), dim3(256), 0, stream>>>(
        x1b, W1t, b1, h, nullptr, M, DFF, D, D, D, 4, 8, 16, 1 << 20);
    // FFN2 split-K x2, BN=64 (R8 best): 16n x (32m x 2kh) = 1024 blocks, K=2048
    mgemm_k<EP_PART, false, 64><<<dim3(1024), dim3(256), 0, stream>>>(
        h, W2t, nullptr, PF0, PF1, M, D, 2048, DFF, DFF, 2, 8, 16, 32);
    // lnf2: x_out = ln2(x1 + PF0 + PF1 + b2) -> d_out
    lnf_k<<<dim3(4096), dim3(256), 0, stream>>>(
        x1, PF0, PF1, b2, g2, be2, (float*)d_out, nullptr);

    (void)in_sizes; (void)n_in; (void)out_size; (void)ws_size;
}

// Round 10
// 411.286 us; speedup vs baseline: 1.0587x; 1.0587x over previous
//
#include <hip/hip_runtime.h>
#include <math.h>

typedef unsigned short u16;
typedef unsigned int u32;
typedef __attribute__((ext_vector_type(8))) short short8v;
typedef __attribute__((ext_vector_type(4))) float f32x4;

__device__ __forceinline__ u16 f2bf(float f) {
    u32 u = __float_as_uint(f);
    u32 r = (u + 0x7fffu + ((u >> 16) & 1u)) >> 16;
    return (u16)r;
}

// async global->LDS DMA, 16 B per lane; lds dst = wave-uniform base + lane*16
#define GLOAD_LDS(g, l)                                                        \
    __builtin_amdgcn_global_load_lds(                                          \
        (const __attribute__((address_space(1))) void*)(g),                    \
        (__attribute__((address_space(3))) void*)(l), 16, 0, 0)

#define SCHED_FENCE() __builtin_amdgcn_sched_barrier(0)

// log2(10000)/512
#define ROPE_LOG2C (13.287712379549449f / 512.0f)

// ================= fused prep kernel =================
__device__ __forceinline__ void cast_body(const float* __restrict__ x,
                                          u16* __restrict__ y, int L, int tid) {
    const int gid = L * 256 + tid;
    float4 v = ((const float4*)x)[gid];
    ushort4 o;
    o.x = f2bf(v.x); o.y = f2bf(v.y); o.z = f2bf(v.z); o.w = f2bf(v.w);
    ((ushort4*)y)[gid] = o;
}

__device__ __forceinline__ void tcast64_body(const float* __restrict__ S,
                                             u16* __restrict__ Dt, int K, int N,
                                             int n0, int k0, int tid,
                                             char* smem) {
    float (*tile)[65] = (float (*)[65])smem;
    const int tx = tid & 15, ty = tid >> 4;
#pragma unroll
    for (int i = 0; i < 4; i++) {
        const int kr = ty + 16 * i;
        const float4 v = *(const float4*)&S[(size_t)(k0 + kr) * N + n0 + tx * 4];
        tile[kr][tx * 4 + 0] = v.x;
        tile[kr][tx * 4 + 1] = v.y;
        tile[kr][tx * 4 + 2] = v.z;
        tile[kr][tx * 4 + 3] = v.w;
    }
    __syncthreads();
#pragma unroll
    for (int i = 0; i < 4; i++) {
        const int nr = ty + 16 * i;
        ushort4 o;
        o.x = f2bf(tile[tx * 4 + 0][nr]);
        o.y = f2bf(tile[tx * 4 + 1][nr]);
        o.z = f2bf(tile[tx * 4 + 2][nr]);
        o.w = f2bf(tile[tx * 4 + 3][nr]);
        *(ushort4*)&Dt[(size_t)(n0 + nr) * K + k0 + tx * 4] = o;
    }
}

__device__ __forceinline__ void rope1_body(const float* __restrict__ A,
                                           float* __restrict__ P, int blk,
                                           int tid, char* smem) {
    float (*sc)[17]  = (float (*)[17])(smem);
    float (*cc)[17]  = (float (*)[17])(smem + 1088);
    float (*Als)[17] = (float (*)[17])(smem + 2176);
    float (*Alc)[17] = (float (*)[17])(smem + 3264);
    const int tt = tid >> 4, rr = tid & 15;
    const int t = blk * 16 + tt;
    float acc = 0.f;
    for (int i0 = 0; i0 < 512; i0 += 16) {
        __syncthreads();
        {
            const int i = i0 + rr;
            const float th = exp2f(-(float)i * ROPE_LOG2C);
            const float ang = (float)t * th;
            sc[tt][rr] = sinf(ang);
            cc[tt][rr] = cosf(ang);
            Als[tt][rr] = A[(i0 + tt) * 16 + rr];
            Alc[tt][rr] = A[(512 + i0 + tt) * 16 + rr];
        }
        __syncthreads();
#pragma unroll
        for (int ii = 0; ii < 16; ++ii)
            acc = fmaf(sc[tt][ii], Als[ii][rr],
                       fmaf(cc[tt][ii], Alc[ii][rr], acc));
    }
    P[t * 16 + rr] = acc;
}

__global__ __launch_bounds__(256) void prep_k(
    const float* __restrict__ tgt, u16* __restrict__ tgtb,
    const float* __restrict__ Wq, u16* __restrict__ Wqt,
    const float* __restrict__ Wk, u16* __restrict__ Wkt,
    const float* __restrict__ Wv, u16* __restrict__ Wvt,
    const float* __restrict__ Wo, u16* __restrict__ Wot,
    const float* __restrict__ W1, u16* __restrict__ W1t,
    const float* __restrict__ W2, u16* __restrict__ W2t,
    const float* __restrict__ rA, float* __restrict__ Pp) {
    __shared__ char smem[64 * 65 * 4];
    const int L = blockIdx.x, tid = threadIdx.x;
    if (L < 128) {                                     // rope pass 1 (longest)
        rope1_body(rA, Pp, L, tid, smem);
    } else if (L < 4224) {                             // cast tgt -> bf16
        cast_body(tgt, tgtb, L - 128, tid);
    } else if (L < 5248) {                             // 4x 1024^2 transpose
        const int i = L - 4224;
        const int r = i >> 8, j = i & 255;
        const float* S = r == 0 ? Wq : (r == 1 ? Wk : (r == 2 ? Wv : Wo));
        u16* Dt = r == 0 ? Wqt : (r == 1 ? Wkt : (r == 2 ? Wvt : Wot));
        tcast64_body(S, Dt, 1024, 1024, (j & 15) * 64, (j >> 4) * 64, tid, smem);
    } else if (L < 6272) {                             // W1 (1024x4096)
        const int j = L - 5248;
        tcast64_body(W1, W1t, 1024, 4096, (j & 63) * 64, (j >> 6) * 64, tid, smem);
    } else {                                           // W2 (4096x1024)
        const int j = L - 6272;
        tcast64_body(W2, W2t, 4096, 1024, (j & 15) * 64, (j >> 4) * 64, tid, smem);
    }
}

// ---------- V transpose per head: vv[m][h*64+d] -> Vt[bh][d][key] ----------
__global__ __launch_bounds__(256) void vtrans_k(const u16* __restrict__ vv,
                                                u16* __restrict__ Vt) {
    __shared__ u16 tile[32][33];
    const int key0 = blockIdx.x * 32, d0 = blockIdx.y * 32, bh = blockIdx.z;
    const int b = bh >> 4, h = bh & 15;
    const int tx = threadIdx.x & 31, ty = threadIdx.x >> 5;
#pragma unroll
    for (int i = 0; i < 4; i++)
        tile[ty + 8 * i][tx] =
            vv[(size_t)(b * 2048 + key0 + ty + 8 * i) * 1024 + h * 64 + d0 + tx];
    __syncthreads();
#pragma unroll
    for (int i = 0; i < 4; i++) {
        const int d = d0 + ty + 8 * i;
        const int key = key0 + tx;
        const int ksw = (key & ~63) | ((((key >> 3) & 7) ^ (d & 7)) << 3) | (key & 7);
        Vt[((size_t)bh * 64 + d) * 2048 + ksw] = tile[tx][ty + 8 * i];
    }
}

// ---------- RoPE pass 2 ----------
__global__ void rope2_k(const float* __restrict__ P, const float* __restrict__ Bw,
                        float* __restrict__ sf, float* __restrict__ cf) {
    const int gid = blockIdx.x * blockDim.x + threadIdx.x;
    if (gid >= 2048 * 512) return;
    const int t = gid >> 9, i = gid & 511;
    float ls = 0.f, lc = 0.f;
#pragma unroll
    for (int r = 0; r < 16; ++r) {
        const float p = P[t * 16 + r];
        ls = fmaf(p, Bw[r * 1024 + i], ls);
        lc = fmaf(p, Bw[r * 1024 + 512 + i], lc);
    }
    const float th = exp2f(-(float)i * ROPE_LOG2C);
    const float ang = (float)t * th;
    sf[gid] = sinf(ang) + ls;
    cf[gid] = cosf(ang) + lc;
}

// XCD supertile mapping: linear grid; xcd = L&7 owns an rn x rm tile region.
__device__ __forceinline__ void xcd_tile(int L, int xn, int rn, int rm,
                                         int& tm, int& tn) {
    const int xcd = L & 7, i = L >> 3;
    const int cx = xcd % xn, cy = xcd / xn;
    tn = cx * rn + (i % rn);
    tm = cy * rm + (i / rn);
}

// ---------- MFMA GEMM (128xBN, 4 waves): 3-stage DMA pipeline ----
// Split-K: tm >= mtiles selects K-half kh=1 (A/Bt advance kh*K columns;
// fp32 partial written to Cp2). lda/ldb are full row strides.
enum { EP_NONE = 0, EP_RELU = 3, EP_PART = 4 };

template <int EPI, bool CBF, int BN>
__global__ __launch_bounds__(256) void mgemm_k(
    const u16* __restrict__ A, const u16* __restrict__ Bt,
    const float* __restrict__ bias, void* __restrict__ Cp,
    void* __restrict__ Cp2, int M, int N, int K, int lda, int ldb,
    int xn, int rn, int rm, int mtiles) {
    constexpr int NT = BN / 32;            // n-frags per wave
    __shared__ u16 As[3 * 128 * 32];
    __shared__ u16 Bs[3 * BN * 32];
    const int tid = threadIdx.x;
    const int w = tid >> 6, l = tid & 63;
    const int quad = l >> 4, lr = l & 15;
    const int wr = w >> 1, wc = w & 1;
    int tm, tn;
    xcd_tile(blockIdx.x, xn, rn, rm, tm, tn);
    int kh = 0;
    if (tm >= mtiles) { kh = 1; tm -= mtiles; }
    const u16* Ak = A + (size_t)kh * K;
    const u16* Bk = Bt + (size_t)kh * K;
    void* Co = kh ? Cp2 : Cp;
    const int m0 = tm * 128, n0 = tn * BN;

    const int srow = w * 16 + (l >> 2);    // staging row (64-row round)
    const int scol = (((l & 3) ^ ((l >> 3) & 3)) * 8);
    const u16* ag0 = Ak + (size_t)(m0 + srow) * lda + scol;
    const u16* ag1 = Ak + (size_t)(m0 + 64 + srow) * lda + scol;
    const u16* bg0 = Bk + (size_t)(n0 + srow) * ldb + scol;
    const u16* bg1 = Bk + (size_t)(n0 + 64 + srow) * ldb + scol;  // BN==128 only

    f32x4 acc[4][NT];
#pragma unroll
    for (int i = 0; i < 4; i++)
#pragma unroll
        for (int j = 0; j < NT; j++) acc[i][j] = (f32x4)(0.0f);

    // prologue: stage tiles 0,1 into buffers 0,1 (issue order = tile order)
    {
        GLOAD_LDS(ag0, As + w * 512);
        GLOAD_LDS(ag1, As + 2048 + w * 512);
        GLOAD_LDS(bg0, Bs + w * 512);
        if (BN == 128) GLOAD_LDS(bg1, Bs + 2048 + w * 512);
        GLOAD_LDS(ag0 + 32, As + 4096 + w * 512);
        GLOAD_LDS(ag1 + 32, As + 4096 + 2048 + w * 512);
        GLOAD_LDS(bg0 + 32, Bs + BN * 32 + w * 512);
        if (BN == 128) GLOAD_LDS(bg1 + 32, Bs + BN * 32 + 2048 + w * 512);
    }

    const int niter = K >> 5;
    const int xsw = ((lr >> 1) & 3) << 3;  // read-side granule XOR (u16 units)
    int bc = 0, bs = 2;                    // compute buf, stage buf (i+2)%3
    for (int i = 0; i < niter; ++i) {
        SCHED_FENCE();
        if (i + 1 < niter) {
            if (BN == 128) asm volatile("s_waitcnt vmcnt(4) lgkmcnt(0)" ::: "memory");
            else           asm volatile("s_waitcnt vmcnt(3) lgkmcnt(0)" ::: "memory");
        } else {
            asm volatile("s_waitcnt vmcnt(0) lgkmcnt(0)" ::: "memory");
        }
        __builtin_amdgcn_s_barrier();
        SCHED_FENCE();
        if (i + 2 < niter) {
            const int kk = (i + 2) << 5;
            u16* Ab = As + bs * 4096;
            u16* Bb = Bs + bs * (BN * 32);
            GLOAD_LDS(ag0 + kk, Ab + w * 512);
            GLOAD_LDS(ag1 + kk, Ab + 2048 + w * 512);
            GLOAD_LDS(bg0 + kk, Bb + w * 512);
            if (BN == 128) GLOAD_LDS(bg1 + kk, Bb + 2048 + w * 512);
        }
        const u16* Ac = As + bc * 4096;
        const u16* Bc = Bs + bc * (BN * 32);
        short8v af[4], bf[NT];
#pragma unroll
        for (int mt = 0; mt < 4; ++mt)
            af[mt] = *(const short8v*)&Ac[(wr * 64 + mt * 16 + lr) * 32 +
                                          ((quad << 3) ^ xsw)];
#pragma unroll
        for (int nt = 0; nt < NT; ++nt)
            bf[nt] = *(const short8v*)&Bc[(wc * (BN / 2) + nt * 16 + lr) * 32 +
                                          ((quad << 3) ^ xsw)];
#pragma unroll
        for (int mt = 0; mt < 4; ++mt)
#pragma unroll
            for (int nt = 0; nt < NT; ++nt)
                acc[mt][nt] = __builtin_amdgcn_mfma_f32_16x16x32_bf16(
                    af[mt], bf[nt], acc[mt][nt], 0, 0, 0);
        bc = (bc == 2) ? 0 : bc + 1;
        bs = (bs == 2) ? 0 : bs + 1;
    }

#pragma unroll
    for (int mt = 0; mt < 4; ++mt) {
#pragma unroll
        for (int nt = 0; nt < NT; ++nt) {
            const int n = n0 + wc * (BN / 2) + nt * 16 + lr;
            const float bb = (EPI == EP_PART) ? 0.0f : bias[n];
#pragma unroll
            for (int reg = 0; reg < 4; ++reg) {
                const int m = m0 + wr * 64 + mt * 16 + quad * 4 + reg;
                float v = acc[mt][nt][reg] + bb;
                if (EPI == EP_RELU) v = fmaxf(v, 0.f);
                if (CBF) ((u16*)Co)[(size_t)m * N + n] = f2bf(v);
                else     ((float*)Co)[(size_t)m * N + n] = v;
            }
        }
    }
}

// ---------- merged QKV GEMM (N=3072), BN=128, 3-stage pipeline, RoPE ----
__global__ __launch_bounds__(256) void mqkv_k(
    const u16* __restrict__ A, const u16* __restrict__ Bt,
    const float* __restrict__ bq, const float* __restrict__ bk,
    const float* __restrict__ bv, const float* __restrict__ sf,
    const float* __restrict__ cf, u16* __restrict__ out) {
    const int K = 1024;
    __shared__ u16 As[3 * 128 * 32];
    __shared__ u16 Bs[3 * 128 * 32];
    const int tid = threadIdx.x;
    const int w = tid >> 6, l = tid & 63;
    const int quad = l >> 4, lr = l & 15;
    const int wr = w >> 1, wc = w & 1;
    int tm, tn;
    xcd_tile(blockIdx.x, 4, 6, 16, tm, tn);   // 24n x 32m grid
    const int m0 = tm * 128, n0 = tn * 128;

    const int srow = w * 16 + (l >> 2);
    const int scol = (((l & 3) ^ ((l >> 3) & 3)) * 8);
    const u16* ag0 = A + (size_t)(m0 + srow) * K + scol;
    const u16* ag1 = A + (size_t)(m0 + 64 + srow) * K + scol;
    const u16* bg0 = Bt + (size_t)(n0 + srow) * K + scol;
    const u16* bg1 = Bt + (size_t)(n0 + 64 + srow) * K + scol;

    f32x4 acc[4][4];
#pragma unroll
    for (int i = 0; i < 4; i++)
#pragma unroll
        for (int j = 0; j < 4; j++) acc[i][j] = (f32x4)(0.0f);

    {
        GLOAD_LDS(ag0, As + w * 512);
        GLOAD_LDS(ag1, As + 2048 + w * 512);
        GLOAD_LDS(bg0, Bs + w * 512);
        GLOAD_LDS(bg1, Bs + 2048 + w * 512);
        GLOAD_LDS(ag0 + 32, As + 4096 + w * 512);
        GLOAD_LDS(ag1 + 32, As + 4096 + 2048 + w * 512);
        GLOAD_LDS(bg0 + 32, Bs + 4096 + w * 512);
        GLOAD_LDS(bg1 + 32, Bs + 4096 + 2048 + w * 512);
    }
    const int xsw = ((lr >> 1) & 3) << 3;
    int bc = 0, bsb = 2;
    for (int i = 0; i < 32; ++i) {
        SCHED_FENCE();
        if (i + 1 < 32) {
            asm volatile("s_waitcnt vmcnt(4) lgkmcnt(0)" ::: "memory");
        } else {
            asm volatile("s_waitcnt vmcnt(0) lgkmcnt(0)" ::: "memory");
        }
        __builtin_amdgcn_s_barrier();
        SCHED_FENCE();
        if (i + 2 < 32) {
            const int kk = (i + 2) << 5;
            u16* Ab = As + bsb * 4096;
            u16* Bb = Bs + bsb * 4096;
            GLOAD_LDS(ag0 + kk, Ab + w * 512);
            GLOAD_LDS(ag1 + kk, Ab + 2048 + w * 512);
            GLOAD_LDS(bg0 + kk, Bb + w * 512);
            GLOAD_LDS(bg1 + kk, Bb + 2048 + w * 512);
        }
        const u16* Ac = As + bc * 4096;
        const u16* Bc = Bs + bc * 4096;
        short8v af[4], bf[4];
#pragma unroll
        for (int mt = 0; mt < 4; ++mt)
            af[mt] = *(const short8v*)&Ac[(wr * 64 + mt * 16 + lr) * 32 +
                                          ((quad << 3) ^ xsw)];
#pragma unroll
        for (int nt = 0; nt < 4; ++nt)
            bf[nt] = *(const short8v*)&Bc[(wc * 64 + nt * 16 + lr) * 32 +
                                          ((quad << 3) ^ xsw)];
#pragma unroll
        for (int mt = 0; mt < 4; ++mt)
#pragma unroll
            for (int nt = 0; nt < 4; ++nt)
                acc[mt][nt] = __builtin_amdgcn_mfma_f32_16x16x32_bf16(
                    af[mt], bf[nt], acc[mt][nt], 0, 0, 0);
        bc = (bc == 2) ? 0 : bc + 1;
        bsb = (bsb == 2) ? 0 : bsb + 1;
    }

    const int which = n0 >> 10;  // block-uniform (1024-boundaries align)
    const float* bias = which == 0 ? bq : (which == 1 ? bk : bv);
    const bool doRope = which < 2;
    u16* Cp = out + (size_t)which * 4096 * 1024;

#pragma unroll
    for (int mt = 0; mt < 4; ++mt) {
#pragma unroll
        for (int nt = 0; nt < 4; ++nt) {
            const int n = n0 + wc * 64 + nt * 16 + lr;
            const int col = n & 1023;
            const float bb = bias[col];
#pragma unroll
            for (int reg = 0; reg < 4; ++reg) {
                const int m = m0 + wr * 64 + mt * 16 + quad * 4 + reg;
                float v = acc[mt][nt][reg] + bb;
                const float partner = __shfl_xor(v, 1);
                int colw = col;
                if (doRope) {
                    const int t = m & 2047;
                    const int fi = col >> 1;
                    const float svv = sf[t * 512 + fi];
                    const float cvv = cf[t * 512 + fi];
                    v = (col & 1) ? fmaf(partner, svv, v * cvv)
                                  : fmaf(v, cvv, -partner * svv);
                    if (which == 0) v *= 0.125f;
                    colw = (col & ~63) | ((((col >> 3) & 7) ^ (m & 7)) << 3) |
                           (col & 7);
                }
                Cp[(size_t)m * 1024 + colw] = f2bf(v);
            }
        }
    }
}

// ---------- MFMA flash attention v2 ----------
// 512 blocks, 4 waves, 128 q-rows/block (32/wave), KVBLK=64 double-buffered.
__global__ __launch_bounds__(256, 3) void mattn_k(
    const u16* __restrict__ Q, const u16* __restrict__ Kg,
    const u16* __restrict__ Vt, u16* __restrict__ O) {
    __shared__ u16 QPs[128 * 64];     // Q staging (prologue), then P tiles
    __shared__ u16 Ks[2][64 * 64];
    __shared__ u16 Vs[2][64 * 64];
    const int tid = threadIdx.x;
    const int w = tid >> 6, l = tid & 63;
    const int quad = l >> 4, lr = l & 15;
    const int L = blockIdx.x;                      // 512 blocks
    const int bh = (L & 7) * 4 + ((L >> 3) & 3);   // 4 bh per XCD (L2 locality)
    const int b = bh >> 4, h = bh & 15;
    const int row0 = (L >> 5) * 128;
    const size_t base = (size_t)b * 2048 * 1024 + (size_t)h * 64;
    const size_t vbase = (size_t)bh * 64 * 2048;

    const int dr = l >> 3;
    const int dc = (l & 7) * 8;
    const int g0 = w * 2, g1 = g0 + 1;
    const u16* kg0 = Kg + base + (size_t)(g0 * 8 + dr) * 1024 + dc;
    const u16* kg1 = Kg + base + (size_t)(g1 * 8 + dr) * 1024 + dc;
    const u16* vg0 = Vt + vbase + (size_t)(g0 * 8 + dr) * 2048 + dc;
    const u16* vg1 = Vt + vbase + (size_t)(g1 * 8 + dr) * 2048 + dc;

#pragma unroll
    for (int j = 0; j < 4; ++j) {
        const int g = w * 4 + j;
        GLOAD_LDS(Q + base + (size_t)(row0 + g * 8 + dr) * 1024 + dc,
                  QPs + g * 512);
    }
    GLOAD_LDS(kg0, Ks[0] + g0 * 512);
    GLOAD_LDS(kg1, Ks[0] + g1 * 512);
    GLOAD_LDS(vg0, Vs[0] + g0 * 512);
    GLOAD_LDS(vg1, Vs[0] + g1 * 512);
    __syncthreads();

    const int rsw = lr & 7;
    short8v qf[2][2];
#pragma unroll
    for (int ntq = 0; ntq < 2; ++ntq) {
        const int qr = w * 32 + ntq * 16 + lr;
#pragma unroll
        for (int kh = 0; kh < 2; ++kh)
            qf[ntq][kh] = *(const short8v*)&QPs[qr * 64 +
                (((kh * 4 + quad) ^ rsw) << 3)];
    }

    f32x4 o_acc[2][4];
#pragma unroll
    for (int i = 0; i < 2; ++i)
#pragma unroll
        for (int j = 0; j < 4; ++j) o_acc[i][j] = (f32x4)(0.0f);
    float lsum[2] = {0.f, 0.f};

    for (int i = 0; i < 32; ++i) {
        __syncthreads();
        if (i + 1 < 32) {
            const size_t kro = (size_t)((i + 1) << 6) * 1024;
            const int kco = (i + 1) << 6;
            u16* Kb = Ks[(i + 1) & 1];
            u16* Vb = Vs[(i + 1) & 1];
            GLOAD_LDS(kg0 + kro, Kb + g0 * 512);
            GLOAD_LDS(kg1 + kro, Kb + g1 * 512);
            GLOAD_LDS(vg0 + kco, Vb + g0 * 512);
            GLOAD_LDS(vg1 + kco, Vb + g1 * 512);
        }
        const u16* Kc = Ks[i & 1];
        const u16* Vc = Vs[i & 1];

        f32x4 s[4][2];
#pragma unroll
        for (int mt = 0; mt < 4; ++mt)
#pragma unroll
            for (int ntq = 0; ntq < 2; ++ntq) s[mt][ntq] = (f32x4)(0.0f);
#pragma unroll
        for (int mt = 0; mt < 4; ++mt) {
            const int kr = mt * 16 + lr;
            const short8v kf0 = *(const short8v*)&Kc[kr * 64 + ((quad ^ rsw) << 3)];
            const short8v kf1 = *(const short8v*)&Kc[kr * 64 + (((quad + 4) ^ rsw) << 3)];
#pragma unroll
            for (int ntq = 0; ntq < 2; ++ntq) {
                s[mt][ntq] = __builtin_amdgcn_mfma_f32_16x16x32_bf16(
                    kf0, qf[ntq][0], s[mt][ntq], 0, 0, 0);
                s[mt][ntq] = __builtin_amdgcn_mfma_f32_16x16x32_bf16(
                    kf1, qf[ntq][1], s[mt][ntq], 0, 0, 0);
            }
        }

#pragma unroll
        for (int ntq = 0; ntq < 2; ++ntq) {
            const int prow = w * 32 + ntq * 16 + lr;
#pragma unroll
            for (int mt = 0; mt < 4; ++mt) {
                const float e0 = __expf(s[mt][ntq][0]);
                const float e1 = __expf(s[mt][ntq][1]);
                const float e2 = __expf(s[mt][ntq][2]);
                const float e3 = __expf(s[mt][ntq][3]);
                lsum[ntq] += (e0 + e1) + (e2 + e3);
                u32 p01, p23;
                asm("v_cvt_pk_bf16_f32 %0, %1, %2" : "=v"(p01) : "v"(e0), "v"(e1));
                asm("v_cvt_pk_bf16_f32 %0, %1, %2" : "=v"(p23) : "v"(e2), "v"(e3));
                uint2 pv; pv.x = p01; pv.y = p23;
                *(uint2*)&QPs[prow * 64 +
                              (((mt * 2 + (quad >> 1)) ^ rsw) << 3) +
                              (quad & 1) * 4] = pv;
            }
        }

        short8v vf[4][2];
#pragma unroll
        for (int ntd = 0; ntd < 4; ++ntd) {
            const int vr = ntd * 16 + lr;
            vf[ntd][0] = *(const short8v*)&Vc[vr * 64 + ((quad ^ rsw) << 3)];
            vf[ntd][1] = *(const short8v*)&Vc[vr * 64 + (((quad + 4) ^ rsw) << 3)];
        }
        short8v pf[2][2];
#pragma unroll
        for (int mtq = 0; mtq < 2; ++mtq) {
            const int prow = w * 32 + mtq * 16 + lr;
            pf[mtq][0] = *(const short8v*)&QPs[prow * 64 + ((quad ^ rsw) << 3)];
            pf[mtq][1] = *(const short8v*)&QPs[prow * 64 + (((quad + 4) ^ rsw) << 3)];
        }
#pragma unroll
        for (int mtq = 0; mtq < 2; ++mtq)
#pragma unroll
            for (int ntd = 0; ntd < 4; ++ntd) {
                o_acc[mtq][ntd] = __builtin_amdgcn_mfma_f32_16x16x32_bf16(
                    pf[mtq][0], vf[ntd][0], o_acc[mtq][ntd], 0, 0, 0);
                o_acc[mtq][ntd] = __builtin_amdgcn_mfma_f32_16x16x32_bf16(
                    pf[mtq][1], vf[ntd][1], o_acc[mtq][ntd], 0, 0, 0);
            }
    }

    float rden[2];
#pragma unroll
    for (int ntq = 0; ntq < 2; ++ntq) {
        float t = lsum[ntq];
        t += __shfl_xor(t, 16);
        t += __shfl_xor(t, 32);
        rden[ntq] = 1.0f / t;
    }
#pragma unroll
    for (int mtq = 0; mtq < 2; ++mtq) {
#pragma unroll
        for (int reg = 0; reg < 4; ++reg) {
            const float dsc = __shfl(rden[mtq], quad * 4 + reg);
            const int m = row0 + w * 32 + mtq * 16 + quad * 4 + reg;
#pragma unroll
            for (int ntd = 0; ntd < 4; ++ntd)
                O[base + (size_t)m * 1024 + ntd * 16 + lr] =
                    f2bf(o_acc[mtq][ntd][reg] * dsc);
        }
    }
}

// ---------- fused partial-sum + bias + layernorm over 1024 cols ----------
__global__ __launch_bounds__(256) void lnf_k(
    const float* __restrict__ X, const float* __restrict__ P0,
    const float* __restrict__ P1, const float* __restrict__ cb,
    const float* __restrict__ g, const float* __restrict__ bb,
    float* __restrict__ outf, u16* __restrict__ outb) {
    const int row = blockIdx.x, tid = threadIdx.x;
    const size_t off = (size_t)row * 1024 + tid * 4;
    float4 xv = *(const float4*)&X[off];
    float4 p0 = *(const float4*)&P0[off];
    float4 p1 = *(const float4*)&P1[off];
    float4 c4 = *(const float4*)&cb[tid * 4];
    xv.x += p0.x + p1.x + c4.x;
    xv.y += p0.y + p1.y + c4.y;
    xv.z += p0.z + p1.z + c4.z;
    xv.w += p0.w + p1.w + c4.w;
    float s = xv.x + xv.y + xv.z + xv.w;
    float s2 = xv.x * xv.x + xv.y * xv.y + xv.z * xv.z + xv.w * xv.w;
#pragma unroll
    for (int msk = 32; msk >= 1; msk >>= 1) {
        s += __shfl_xor(s, msk);
        s2 += __shfl_xor(s2, msk);
    }
    __shared__ float red[8];
    const int wv = tid >> 6;
    if ((tid & 63) == 0) { red[wv] = s; red[wv + 4] = s2; }
    __syncthreads();
    s = red[0] + red[1] + red[2] + red[3];
    s2 = red[4] + red[5] + red[6] + red[7];
    const float mu = s * (1.f / 1024.f);
    float var = s2 * (1.f / 1024.f) - mu * mu;
    var = fmaxf(var, 0.f);
    const float rstd = rsqrtf(var + 1e-5f);
    float4 g4 = *(const float4*)&g[tid * 4];
    float4 b4 = *(const float4*)&bb[tid * 4];
    float o0 = (xv.x - mu) * rstd * g4.x + b4.x;
    float o1 = (xv.y - mu) * rstd * g4.y + b4.y;
    float o2 = (xv.z - mu) * rstd * g4.z + b4.z;
    float o3 = (xv.w - mu) * rstd * g4.w + b4.w;
    if (outf)
        *(float4*)(outf + off) = make_float4(o0, o1, o2, o3);
    if (outb) {
        ushort4 ov;
        ov.x = f2bf(o0); ov.y = f2bf(o1); ov.z = f2bf(o2); ov.w = f2bf(o3);
        *(ushort4*)(outb + off) = ov;
    }
}

extern "C" void kernel_launch(void* const* d_in, const int* in_sizes, int n_in,
                              void* d_out, int out_size, void* d_ws, size_t ws_size,
                              hipStream_t stream) {
    const float* tgt = (const float*)d_in[0];
    const float* Wq  = (const float*)d_in[1];
    const float* bq  = (const float*)d_in[2];
    const float* Wk  = (const float*)d_in[3];
    const float* bk  = (const float*)d_in[4];
    const float* Wv  = (const float*)d_in[5];
    const float* bv  = (const float*)d_in[6];
    const float* Wo  = (const float*)d_in[7];
    const float* bo  = (const float*)d_in[8];
    const float* W1  = (const float*)d_in[9];
    const float* b1  = (const float*)d_in[10];
    const float* W2  = (const float*)d_in[11];
    const float* b2  = (const float*)d_in[12];
    const float* g1  = (const float*)d_in[13];
    const float* be1 = (const float*)d_in[14];
    const float* g2  = (const float*)d_in[15];
    const float* be2 = (const float*)d_in[16];
    const float* rA  = (const float*)d_in[17];
    const float* rB  = (const float*)d_in[18];

    const int M = 4096, D = 1024, DFF = 4096;
    const size_t MD = (size_t)M * D;
    const size_t MB = 1u << 20;
    char* wsb = (char*)d_ws;

    // Lifetime-aliased layout (88 MB total):
    // [0,16)  Pp(tmp) -> q,kk (mqkv->mattn) -> PW0 (Wo->lnf1) -> h[0,16)
    // [16,24) vv (mqkv->vtrans) -> ctx (mattn->Wo) -> h[16,24)
    // [24,32) Vt (vtrans->mattn) -> h[24,32)
    // [32,48) sfp,cfp + tgtb (->mqkv) -> PW1 (Wo->lnf1) -> PF1 (FFN2->lnf2)
    // [48,64) x1 fp32 (lnf1->lnf2)
    // [64,72) Wqt..Wot (->mqkv/Wo) -> x1b (lnf1->FFN1) -> PF0 lo
    // [72,80) W1t (->FFN1) -> PF0 hi
    // [80,88) W2t (->FFN2)
    u16* q    = (u16*)wsb;
    u16* vv   = q + 2 * MD;
    u16* ctx  = (u16*)(wsb + 16 * MB);
    u16* Vt   = (u16*)(wsb + 24 * MB);
    u16* h    = q;
    float* PW0 = (float*)wsb;
    float* PW1 = (float*)(wsb + 32 * MB);
    float* PF0 = (float*)(wsb + 64 * MB);
    float* PF1 = (float*)(wsb + 32 * MB);
    float* sfp = (float*)(wsb + 32 * MB);
    float* cfp = sfp + (size_t)2048 * 512;
    u16* tgtb = (u16*)(wsb + 40 * MB);
    float* x1  = (float*)(wsb + 48 * MB);
    u16* x1b  = (u16*)(wsb + 64 * MB);
    u16* Wqt  = (u16*)(wsb + 64 * MB);
    u16* Wkt  = (u16*)(wsb + 66 * MB);
    u16* Wvt  = (u16*)(wsb + 68 * MB);
    u16* Wot  = (u16*)(wsb + 70 * MB);
    u16* W1t  = (u16*)(wsb + 72 * MB);
    u16* W2t  = (u16*)(wsb + 80 * MB);
    float* Pp = (float*)wsb;               // 128 KB, dead before mqkv

    // fused prep: rope1 + cast + 6 weight transposes (one launch)
    prep_k<<<dim3(7296), dim3(256), 0, stream>>>(
        tgt, tgtb, Wq, Wqt, Wk, Wkt, Wv, Wvt, Wo, Wot,
        W1, W1t, W2, W2t, rA, Pp);
    rope2_k<<<dim3(4096), dim3(256), 0, stream>>>(Pp, rB, sfp, cfp);

    // QKV BN=128 (R6 best): 24n x 32m = 768 blocks (3/CU); xn=4 -> 6n x 16m/XCD
    mqkv_k<<<dim3(768), dim3(256), 0, stream>>>(
        tgtb, Wqt, bq, bk, bv, sfp, cfp, q);

    vtrans_k<<<dim3(64, 2, 32), dim3(256), 0, stream>>>(vv, Vt);

    // 512 blocks: 8 xcd x 4 bh x 16 row-tiles (128 q rows each)
    mattn_k<<<dim3(512), dim3(256), 0, stream>>>(q, q + MD, Vt, ctx);

    // Wo split-K x2, BN=128 (R6 best): 8n x (32m x 2kh) = 512 blocks, K=512
    mgemm_k<EP_PART, false, 128><<<dim3(512), dim3(256), 0, stream>>>(
        ctx, Wot, nullptr, PW0, PW1, M, D, 512, D, D, 1, 8, 8, 32);
    // lnf1: x_attn = tgt + PW0 + PW1 + bo -> LN -> x1 (fp32) + x1b (bf16)
    lnf_k<<<dim3(4096), dim3(256), 0, stream>>>(
        tgt, PW0, PW1, bo, g1, be1, x1, x1b);
    // FFN1: BN=128 -> 32n x 32m = 1024 blocks (4/CU); xn=4 -> 8n x 16m per XCD
    mgemm_k<EP_RELU, true, 128><<<dim3(1024), dim3(256), 0, stream>>>(
        x1b, W1t, b1, h, nullptr, M, DFF, D, D, D, 4, 8, 16, 1 << 20);
    // FFN2 split-K x2, BN=64 (R8 best): 16n x (32m x 2kh) = 1024 blocks, K=2048
    mgemm_k<EP_PART, false, 64><<<dim3(1024), dim3(256), 0, stream>>>(
        h, W2t, nullptr, PF0, PF1, M, D, 2048, DFF, DFF, 2, 8, 16, 32);
    // lnf2: x_out = ln2(x1 + PF0 + PF1 + b2) -> d_out
    lnf_k<<<dim3(4096), dim3(256), 0, stream>>>(
        x1, PF0, PF1, b2, g2, be2, (float*)d_out, nullptr);

    (void)in_sizes; (void)n_in; (void)out_size; (void)ws_size;
}

// Round 11
// 402.756 us; speedup vs baseline: 1.0811x; 1.0212x over previous
//
#include <hip/hip_runtime.h>
#include <math.h>

typedef unsigned short u16;
typedef unsigned int u32;
typedef __attribute__((ext_vector_type(8))) short short8v;
typedef __attribute__((ext_vector_type(4))) float f32x4;

__device__ __forceinline__ u16 f2bf(float f) {
    u32 u = __float_as_uint(f);
    u32 r = (u + 0x7fffu + ((u >> 16) & 1u)) >> 16;
    return (u16)r;
}

// async global->LDS DMA, 16 B per lane; lds dst = wave-uniform base + lane*16
#define GLOAD_LDS(g, l)                                                        \
    __builtin_amdgcn_global_load_lds(                                          \
        (const __attribute__((address_space(1))) void*)(g),                    \
        (__attribute__((address_space(3))) void*)(l), 16, 0, 0)

#define SCHED_FENCE() __builtin_amdgcn_sched_barrier(0)

// log2(10000)/512
#define ROPE_LOG2C (13.287712379549449f / 512.0f)

// ================= fused prep kernel =================
// One launch replacing {rope1, rope2, cast, tcast x6}. The rope role is
// self-contained: each block (one t) recomputes P[t][0..16) itself
// (67 MFLOP total chip-wide) -> no intra-launch ordering dependency.
__device__ __forceinline__ void cast_body(const float* __restrict__ x,
                                          u16* __restrict__ y, int L, int tid) {
    const int gid = L * 256 + tid;
    float4 v = ((const float4*)x)[gid];
    ushort4 o;
    o.x = f2bf(v.x); o.y = f2bf(v.y); o.z = f2bf(v.z); o.w = f2bf(v.w);
    ((ushort4*)y)[gid] = o;
}

__device__ __forceinline__ void tcast64_body(const float* __restrict__ S,
                                             u16* __restrict__ Dt, int K, int N,
                                             int n0, int k0, int tid,
                                             char* smem) {
    float (*tile)[65] = (float (*)[65])smem;
    const int tx = tid & 15, ty = tid >> 4;
#pragma unroll
    for (int i = 0; i < 4; i++) {
        const int kr = ty + 16 * i;
        const float4 v = *(const float4*)&S[(size_t)(k0 + kr) * N + n0 + tx * 4];
        tile[kr][tx * 4 + 0] = v.x;
        tile[kr][tx * 4 + 1] = v.y;
        tile[kr][tx * 4 + 2] = v.z;
        tile[kr][tx * 4 + 3] = v.w;
    }
    __syncthreads();
#pragma unroll
    for (int i = 0; i < 4; i++) {
        const int nr = ty + 16 * i;
        ushort4 o;
        o.x = f2bf(tile[tx * 4 + 0][nr]);
        o.y = f2bf(tile[tx * 4 + 1][nr]);
        o.z = f2bf(tile[tx * 4 + 2][nr]);
        o.w = f2bf(tile[tx * 4 + 3][nr]);
        *(ushort4*)&Dt[(size_t)(n0 + nr) * K + k0 + tx * 4] = o;
    }
}

// rope role: one block per t. P[t][r] = sum_j base[t][j]*rA[j][r] computed
// in-block (thread owns 4 j's), tree-reduced; then sf/cf elementwise.
__device__ __forceinline__ void ropef_body(const float* __restrict__ rA,
                                           const float* __restrict__ Bw,
                                           float* __restrict__ sf,
                                           float* __restrict__ cf,
                                           int t, int tid, char* smem) {
    float* red = (float*)smem;   // [4][16] wave sums, [64..80) final P
    float p[16];
#pragma unroll
    for (int r = 0; r < 16; ++r) p[r] = 0.f;
#pragma unroll
    for (int jj = 0; jj < 4; ++jj) {
        const int j = tid * 4 + jj;
        const int i = (j < 512) ? j : (j - 512);
        const float th = exp2f(-(float)i * ROPE_LOG2C);
        const float ang = (float)t * th;
        const float base = (j < 512) ? sinf(ang) : cosf(ang);
        const float4* arow = (const float4*)&rA[j * 16];
        const float4 a0 = arow[0], a1 = arow[1], a2 = arow[2], a3 = arow[3];
        p[0] = fmaf(base, a0.x, p[0]);  p[1] = fmaf(base, a0.y, p[1]);
        p[2] = fmaf(base, a0.z, p[2]);  p[3] = fmaf(base, a0.w, p[3]);
        p[4] = fmaf(base, a1.x, p[4]);  p[5] = fmaf(base, a1.y, p[5]);
        p[6] = fmaf(base, a1.z, p[6]);  p[7] = fmaf(base, a1.w, p[7]);
        p[8] = fmaf(base, a2.x, p[8]);  p[9] = fmaf(base, a2.y, p[9]);
        p[10] = fmaf(base, a2.z, p[10]); p[11] = fmaf(base, a2.w, p[11]);
        p[12] = fmaf(base, a3.x, p[12]); p[13] = fmaf(base, a3.y, p[13]);
        p[14] = fmaf(base, a3.z, p[14]); p[15] = fmaf(base, a3.w, p[15]);
    }
    const int w = tid >> 6, lane = tid & 63;
#pragma unroll
    for (int r = 0; r < 16; ++r) {
        float v = p[r];
        v += __shfl_xor(v, 1);  v += __shfl_xor(v, 2);
        v += __shfl_xor(v, 4);  v += __shfl_xor(v, 8);
        v += __shfl_xor(v, 16); v += __shfl_xor(v, 32);
        if (lane == 0) red[w * 16 + r] = v;
    }
    __syncthreads();
    if (tid < 16)
        red[64 + tid] = red[tid] + red[16 + tid] + red[32 + tid] + red[48 + tid];
    __syncthreads();
#pragma unroll
    for (int half = 0; half < 2; ++half) {
        const int i = tid + half * 256;
        float ls = 0.f, lc = 0.f;
#pragma unroll
        for (int r = 0; r < 16; ++r) {
            const float Pr = red[64 + r];
            ls = fmaf(Pr, Bw[r * 1024 + i], ls);
            lc = fmaf(Pr, Bw[r * 1024 + 512 + i], lc);
        }
        const float th = exp2f(-(float)i * ROPE_LOG2C);
        const float ang = (float)t * th;
        sf[t * 512 + i] = sinf(ang) + ls;
        cf[t * 512 + i] = cosf(ang) + lc;
    }
}

__global__ __launch_bounds__(256) void prep_k(
    const float* __restrict__ tgt, u16* __restrict__ tgtb,
    const float* __restrict__ Wq, u16* __restrict__ Wqt,
    const float* __restrict__ Wk, u16* __restrict__ Wkt,
    const float* __restrict__ Wv, u16* __restrict__ Wvt,
    const float* __restrict__ Wo, u16* __restrict__ Wot,
    const float* __restrict__ W1, u16* __restrict__ W1t,
    const float* __restrict__ W2, u16* __restrict__ W2t,
    const float* __restrict__ rA, const float* __restrict__ Bw,
    float* __restrict__ sf, float* __restrict__ cf) {
    __shared__ char smem[64 * 65 * 4];
    const int L = blockIdx.x, tid = threadIdx.x;
    if (L < 2048) {                                    // rope (self-contained)
        ropef_body(rA, Bw, sf, cf, L, tid, smem);
    } else if (L < 6144) {                             // cast tgt -> bf16
        cast_body(tgt, tgtb, L - 2048, tid);
    } else if (L < 7168) {                             // 4x 1024^2 transpose
        const int i = L - 6144;
        const int r = i >> 8, j = i & 255;
        const float* S = r == 0 ? Wq : (r == 1 ? Wk : (r == 2 ? Wv : Wo));
        u16* Dt = r == 0 ? Wqt : (r == 1 ? Wkt : (r == 2 ? Wvt : Wot));
        tcast64_body(S, Dt, 1024, 1024, (j & 15) * 64, (j >> 4) * 64, tid, smem);
    } else if (L < 8192) {                             // W1 (1024x4096)
        const int j = L - 7168;
        tcast64_body(W1, W1t, 1024, 4096, (j & 63) * 64, (j >> 6) * 64, tid, smem);
    } else {                                           // W2 (4096x1024)
        const int j = L - 8192;
        tcast64_body(W2, W2t, 4096, 1024, (j & 15) * 64, (j >> 4) * 64, tid, smem);
    }
}

// ---------- V transpose per head: vv[m][h*64+d] -> Vt[bh][d][key] ----------
__global__ __launch_bounds__(256) void vtrans_k(const u16* __restrict__ vv,
                                                u16* __restrict__ Vt) {
    __shared__ u16 tile[32][33];
    const int key0 = blockIdx.x * 32, d0 = blockIdx.y * 32, bh = blockIdx.z;
    const int b = bh >> 4, h = bh & 15;
    const int tx = threadIdx.x & 31, ty = threadIdx.x >> 5;
#pragma unroll
    for (int i = 0; i < 4; i++)
        tile[ty + 8 * i][tx] =
            vv[(size_t)(b * 2048 + key0 + ty + 8 * i) * 1024 + h * 64 + d0 + tx];
    __syncthreads();
#pragma unroll
    for (int i = 0; i < 4; i++) {
        const int d = d0 + ty + 8 * i;
        const int key = key0 + tx;
        const int ksw = (key & ~63) | ((((key >> 3) & 7) ^ (d & 7)) << 3) | (key & 7);
        Vt[((size_t)bh * 64 + d) * 2048 + ksw] = tile[tx][ty + 8 * i];
    }
}

// XCD supertile mapping: linear grid; xcd = L&7 owns an rn x rm tile region.
__device__ __forceinline__ void xcd_tile(int L, int xn, int rn, int rm,
                                         int& tm, int& tn) {
    const int xcd = L & 7, i = L >> 3;
    const int cx = xcd % xn, cy = xcd / xn;
    tn = cx * rn + (i % rn);
    tm = cy * rm + (i / rn);
}

// ---------- MFMA GEMM (128xBN, 4 waves): 3-stage DMA pipeline ----
// Split-K: tm >= mtiles selects K-half kh=1 (A/Bt advance kh*K columns;
// fp32 partial written to Cp2). lda/ldb are full row strides.
enum { EP_NONE = 0, EP_RELU = 3, EP_PART = 4 };

template <int EPI, bool CBF, int BN>
__global__ __launch_bounds__(256) void mgemm_k(
    const u16* __restrict__ A, const u16* __restrict__ Bt,
    const float* __restrict__ bias, void* __restrict__ Cp,
    void* __restrict__ Cp2, int M, int N, int K, int lda, int ldb,
    int xn, int rn, int rm, int mtiles) {
    constexpr int NT = BN / 32;            // n-frags per wave
    __shared__ u16 As[3 * 128 * 32];
    __shared__ u16 Bs[3 * BN * 32];
    const int tid = threadIdx.x;
    const int w = tid >> 6, l = tid & 63;
    const int quad = l >> 4, lr = l & 15;
    const int wr = w >> 1, wc = w & 1;
    int tm, tn;
    xcd_tile(blockIdx.x, xn, rn, rm, tm, tn);
    int kh = 0;
    if (tm >= mtiles) { kh = 1; tm -= mtiles; }
    const u16* Ak = A + (size_t)kh * K;
    const u16* Bk = Bt + (size_t)kh * K;
    void* Co = kh ? Cp2 : Cp;
    const int m0 = tm * 128, n0 = tn * BN;

    const int srow = w * 16 + (l >> 2);    // staging row (64-row round)
    const int scol = (((l & 3) ^ ((l >> 3) & 3)) * 8);
    const u16* ag0 = Ak + (size_t)(m0 + srow) * lda + scol;
    const u16* ag1 = Ak + (size_t)(m0 + 64 + srow) * lda + scol;
    const u16* bg0 = Bk + (size_t)(n0 + srow) * ldb + scol;
    const u16* bg1 = Bk + (size_t)(n0 + 64 + srow) * ldb + scol;  // BN==128 only

    f32x4 acc[4][NT];
#pragma unroll
    for (int i = 0; i < 4; i++)
#pragma unroll
        for (int j = 0; j < NT; j++) acc[i][j] = (f32x4)(0.0f);

    // prologue: stage tiles 0,1 into buffers 0,1 (issue order = tile order)
    {
        GLOAD_LDS(ag0, As + w * 512);
        GLOAD_LDS(ag1, As + 2048 + w * 512);
        GLOAD_LDS(bg0, Bs + w * 512);
        if (BN == 128) GLOAD_LDS(bg1, Bs + 2048 + w * 512);
        GLOAD_LDS(ag0 + 32, As + 4096 + w * 512);
        GLOAD_LDS(ag1 + 32, As + 4096 + 2048 + w * 512);
        GLOAD_LDS(bg0 + 32, Bs + BN * 32 + w * 512);
        if (BN == 128) GLOAD_LDS(bg1 + 32, Bs + BN * 32 + 2048 + w * 512);
    }

    const int niter = K >> 5;
    const int xsw = ((lr >> 1) & 3) << 3;  // read-side granule XOR (u16 units)
    int bc = 0, bs = 2;                    // compute buf, stage buf (i+2)%3
    for (int i = 0; i < niter; ++i) {
        SCHED_FENCE();
        if (i + 1 < niter) {
            if (BN == 128) asm volatile("s_waitcnt vmcnt(4) lgkmcnt(0)" ::: "memory");
            else           asm volatile("s_waitcnt vmcnt(3) lgkmcnt(0)" ::: "memory");
        } else {
            asm volatile("s_waitcnt vmcnt(0) lgkmcnt(0)" ::: "memory");
        }
        __builtin_amdgcn_s_barrier();
        SCHED_FENCE();
        if (i + 2 < niter) {
            const int kk = (i + 2) << 5;
            u16* Ab = As + bs * 4096;
            u16* Bb = Bs + bs * (BN * 32);
            GLOAD_LDS(ag0 + kk, Ab + w * 512);
            GLOAD_LDS(ag1 + kk, Ab + 2048 + w * 512);
            GLOAD_LDS(bg0 + kk, Bb + w * 512);
            if (BN == 128) GLOAD_LDS(bg1 + kk, Bb + 2048 + w * 512);
        }
        const u16* Ac = As + bc * 4096;
        const u16* Bc = Bs + bc * (BN * 32);
        short8v af[4], bf[NT];
#pragma unroll
        for (int mt = 0; mt < 4; ++mt)
            af[mt] = *(const short8v*)&Ac[(wr * 64 + mt * 16 + lr) * 32 +
                                          ((quad << 3) ^ xsw)];
#pragma unroll
        for (int nt = 0; nt < NT; ++nt)
            bf[nt] = *(const short8v*)&Bc[(wc * (BN / 2) + nt * 16 + lr) * 32 +
                                          ((quad << 3) ^ xsw)];
#pragma unroll
        for (int mt = 0; mt < 4; ++mt)
#pragma unroll
            for (int nt = 0; nt < NT; ++nt)
                acc[mt][nt] = __builtin_amdgcn_mfma_f32_16x16x32_bf16(
                    af[mt], bf[nt], acc[mt][nt], 0, 0, 0);
        bc = (bc == 2) ? 0 : bc + 1;
        bs = (bs == 2) ? 0 : bs + 1;
    }

#pragma unroll
    for (int mt = 0; mt < 4; ++mt) {
#pragma unroll
        for (int nt = 0; nt < NT; ++nt) {
            const int n = n0 + wc * (BN / 2) + nt * 16 + lr;
            const float bb = (EPI == EP_PART) ? 0.0f : bias[n];
#pragma unroll
            for (int reg = 0; reg < 4; ++reg) {
                const int m = m0 + wr * 64 + mt * 16 + quad * 4 + reg;
                float v = acc[mt][nt][reg] + bb;
                if (EPI == EP_RELU) v = fmaxf(v, 0.f);
                if (CBF) ((u16*)Co)[(size_t)m * N + n] = f2bf(v);
                else     ((float*)Co)[(size_t)m * N + n] = v;
            }
        }
    }
}

// ---------- merged QKV GEMM (N=3072), BN=128, 3-stage pipeline, RoPE ----
__global__ __launch_bounds__(256) void mqkv_k(
    const u16* __restrict__ A, const u16* __restrict__ Bt,
    const float* __restrict__ bq, const float* __restrict__ bk,
    const float* __restrict__ bv, const float* __restrict__ sf,
    const float* __restrict__ cf, u16* __restrict__ out) {
    const int K = 1024;
    __shared__ u16 As[3 * 128 * 32];
    __shared__ u16 Bs[3 * 128 * 32];
    const int tid = threadIdx.x;
    const int w = tid >> 6, l = tid & 63;
    const int quad = l >> 4, lr = l & 15;
    const int wr = w >> 1, wc = w & 1;
    int tm, tn;
    xcd_tile(blockIdx.x, 4, 6, 16, tm, tn);   // 24n x 32m grid
    const int m0 = tm * 128, n0 = tn * 128;

    const int srow = w * 16 + (l >> 2);
    const int scol = (((l & 3) ^ ((l >> 3) & 3)) * 8);
    const u16* ag0 = A + (size_t)(m0 + srow) * K + scol;
    const u16* ag1 = A + (size_t)(m0 + 64 + srow) * K + scol;
    const u16* bg0 = Bt + (size_t)(n0 + srow) * K + scol;
    const u16* bg1 = Bt + (size_t)(n0 + 64 + srow) * K + scol;

    f32x4 acc[4][4];
#pragma unroll
    for (int i = 0; i < 4; i++)
#pragma unroll
        for (int j = 0; j < 4; j++) acc[i][j] = (f32x4)(0.0f);

    {
        GLOAD_LDS(ag0, As + w * 512);
        GLOAD_LDS(ag1, As + 2048 + w * 512);
        GLOAD_LDS(bg0, Bs + w * 512);
        GLOAD_LDS(bg1, Bs + 2048 + w * 512);
        GLOAD_LDS(ag0 + 32, As + 4096 + w * 512);
        GLOAD_LDS(ag1 + 32, As + 4096 + 2048 + w * 512);
        GLOAD_LDS(bg0 + 32, Bs + 4096 + w * 512);
        GLOAD_LDS(bg1 + 32, Bs + 4096 + 2048 + w * 512);
    }
    const int xsw = ((lr >> 1) & 3) << 3;
    int bc = 0, bsb = 2;
    for (int i = 0; i < 32; ++i) {
        SCHED_FENCE();
        if (i + 1 < 32) {
            asm volatile("s_waitcnt vmcnt(4) lgkmcnt(0)" ::: "memory");
        } else {
            asm volatile("s_waitcnt vmcnt(0) lgkmcnt(0)" ::: "memory");
        }
        __builtin_amdgcn_s_barrier();
        SCHED_FENCE();
        if (i + 2 < 32) {
            const int kk = (i + 2) << 5;
            u16* Ab = As + bsb * 4096;
            u16* Bb = Bs + bsb * 4096;
            GLOAD_LDS(ag0 + kk, Ab + w * 512);
            GLOAD_LDS(ag1 + kk, Ab + 2048 + w * 512);
            GLOAD_LDS(bg0 + kk, Bb + w * 512);
            GLOAD_LDS(bg1 + kk, Bb + 4096 + w * 512 - 4096 + 2048);
        }
        const u16* Ac = As + bc * 4096;
        const u16* Bc = Bs + bc * 4096;
        short8v af[4], bf[4];
#pragma unroll
        for (int mt = 0; mt < 4; ++mt)
            af[mt] = *(const short8v*)&Ac[(wr * 64 + mt * 16 + lr) * 32 +
                                          ((quad << 3) ^ xsw)];
#pragma unroll
        for (int nt = 0; nt < 4; ++nt)
            bf[nt] = *(const short8v*)&Bc[(wc * 64 + nt * 16 + lr) * 32 +
                                          ((quad << 3) ^ xsw)];
#pragma unroll
        for (int mt = 0; mt < 4; ++mt)
#pragma unroll
            for (int nt = 0; nt < 4; ++nt)
                acc[mt][nt] = __builtin_amdgcn_mfma_f32_16x16x32_bf16(
                    af[mt], bf[nt], acc[mt][nt], 0, 0, 0);
        bc = (bc == 2) ? 0 : bc + 1;
        bsb = (bsb == 2) ? 0 : bsb + 1;
    }

    const int which = n0 >> 10;  // block-uniform (1024-boundaries align)
    const float* bias = which == 0 ? bq : (which == 1 ? bk : bv);
    const bool doRope = which < 2;
    u16* Cp = out + (size_t)which * 4096 * 1024;

#pragma unroll
    for (int mt = 0; mt < 4; ++mt) {
#pragma unroll
        for (int nt = 0; nt < 4; ++nt) {
            const int n = n0 + wc * 64 + nt * 16 + lr;
            const int col = n & 1023;
            const float bb = bias[col];
#pragma unroll
            for (int reg = 0; reg < 4; ++reg) {
                const int m = m0 + wr * 64 + mt * 16 + quad * 4 + reg;
                float v = acc[mt][nt][reg] + bb;
                const float partner = __shfl_xor(v, 1);
                int colw = col;
                if (doRope) {
                    const int t = m & 2047;
                    const int fi = col >> 1;
                    const float svv = sf[t * 512 + fi];
                    const float cvv = cf[t * 512 + fi];
                    v = (col & 1) ? fmaf(partner, svv, v * cvv)
                                  : fmaf(v, cvv, -partner * svv);
                    if (which == 0) v *= 0.125f;
                    colw = (col & ~63) | ((((col >> 3) & 7) ^ (m & 7)) << 3) |
                           (col & 7);
                }
                Cp[(size_t)m * 1024 + colw] = f2bf(v);
            }
        }
    }
}

// ---------- MFMA flash attention v2 ----------
// 512 blocks, 4 waves, 128 q-rows/block (32/wave), KVBLK=64 double-buffered.
__global__ __launch_bounds__(256, 3) void mattn_k(
    const u16* __restrict__ Q, const u16* __restrict__ Kg,
    const u16* __restrict__ Vt, u16* __restrict__ O) {
    __shared__ u16 QPs[128 * 64];     // Q staging (prologue), then P tiles
    __shared__ u16 Ks[2][64 * 64];
    __shared__ u16 Vs[2][64 * 64];
    const int tid = threadIdx.x;
    const int w = tid >> 6, l = tid & 63;
    const int quad = l >> 4, lr = l & 15;
    const int L = blockIdx.x;                      // 512 blocks
    const int bh = (L & 7) * 4 + ((L >> 3) & 3);   // 4 bh per XCD (L2 locality)
    const int b = bh >> 4, h = bh & 15;
    const int row0 = (L >> 5) * 128;
    const size_t base = (size_t)b * 2048 * 1024 + (size_t)h * 64;
    const size_t vbase = (size_t)bh * 64 * 2048;

    const int dr = l >> 3;
    const int dc = (l & 7) * 8;
    const int g0 = w * 2, g1 = g0 + 1;
    const u16* kg0 = Kg + base + (size_t)(g0 * 8 + dr) * 1024 + dc;
    const u16* kg1 = Kg + base + (size_t)(g1 * 8 + dr) * 1024 + dc;
    const u16* vg0 = Vt + vbase + (size_t)(g0 * 8 + dr) * 2048 + dc;
    const u16* vg1 = Vt + vbase + (size_t)(g1 * 8 + dr) * 2048 + dc;

#pragma unroll
    for (int j = 0; j < 4; ++j) {
        const int g = w * 4 + j;
        GLOAD_LDS(Q + base + (size_t)(row0 + g * 8 + dr) * 1024 + dc,
                  QPs + g * 512);
    }
    GLOAD_LDS(kg0, Ks[0] + g0 * 512);
    GLOAD_LDS(kg1, Ks[0] + g1 * 512);
    GLOAD_LDS(vg0, Vs[0] + g0 * 512);
    GLOAD_LDS(vg1, Vs[0] + g1 * 512);
    __syncthreads();

    const int rsw = lr & 7;
    short8v qf[2][2];
#pragma unroll
    for (int ntq = 0; ntq < 2; ++ntq) {
        const int qr = w * 32 + ntq * 16 + lr;
#pragma unroll
        for (int kh = 0; kh < 2; ++kh)
            qf[ntq][kh] = *(const short8v*)&QPs[qr * 64 +
                (((kh * 4 + quad) ^ rsw) << 3)];
    }

    f32x4 o_acc[2][4];
#pragma unroll
    for (int i = 0; i < 2; ++i)
#pragma unroll
        for (int j = 0; j < 4; ++j) o_acc[i][j] = (f32x4)(0.0f);
    float lsum[2] = {0.f, 0.f};

    for (int i = 0; i < 32; ++i) {
        __syncthreads();
        if (i + 1 < 32) {
            const size_t kro = (size_t)((i + 1) << 6) * 1024;
            const int kco = (i + 1) << 6;
            u16* Kb = Ks[(i + 1) & 1];
            u16* Vb = Vs[(i + 1) & 1];
            GLOAD_LDS(kg0 + kro, Kb + g0 * 512);
            GLOAD_LDS(kg1 + kro, Kb + g1 * 512);
            GLOAD_LDS(vg0 + kco, Vb + g0 * 512);
            GLOAD_LDS(vg1 + kco, Vb + g1 * 512);
        }
        const u16* Kc = Ks[i & 1];
        const u16* Vc = Vs[i & 1];

        f32x4 s[4][2];
#pragma unroll
        for (int mt = 0; mt < 4; ++mt)
#pragma unroll
            for (int ntq = 0; ntq < 2; ++ntq) s[mt][ntq] = (f32x4)(0.0f);
#pragma unroll
        for (int mt = 0; mt < 4; ++mt) {
            const int kr = mt * 16 + lr;
            const short8v kf0 = *(const short8v*)&Kc[kr * 64 + ((quad ^ rsw) << 3)];
            const short8v kf1 = *(const short8v*)&Kc[kr * 64 + (((quad + 4) ^ rsw) << 3)];
#pragma unroll
            for (int ntq = 0; ntq < 2; ++ntq) {
                s[mt][ntq] = __builtin_amdgcn_mfma_f32_16x16x32_bf16(
                    kf0, qf[ntq][0], s[mt][ntq], 0, 0, 0);
                s[mt][ntq] = __builtin_amdgcn_mfma_f32_16x16x32_bf16(
                    kf1, qf[ntq][1], s[mt][ntq], 0, 0, 0);
            }
        }

#pragma unroll
        for (int ntq = 0; ntq < 2; ++ntq) {
            const int prow = w * 32 + ntq * 16 + lr;
#pragma unroll
            for (int mt = 0; mt < 4; ++mt) {
                const float e0 = __expf(s[mt][ntq][0]);
                const float e1 = __expf(s[mt][ntq][1]);
                const float e2 = __expf(s[mt][ntq][2]);
                const float e3 = __expf(s[mt][ntq][3]);
                lsum[ntq] += (e0 + e1) + (e2 + e3);
                u32 p01, p23;
                asm("v_cvt_pk_bf16_f32 %0, %1, %2" : "=v"(p01) : "v"(e0), "v"(e1));
                asm("v_cvt_pk_bf16_f32 %0, %1, %2" : "=v"(p23) : "v"(e2), "v"(e3));
                uint2 pv; pv.x = p01; pv.y = p23;
                *(uint2*)&QPs[prow * 64 +
                              (((mt * 2 + (quad >> 1)) ^ rsw) << 3) +
                              (quad & 1) * 4] = pv;
            }
        }

        short8v vf[4][2];
#pragma unroll
        for (int ntd = 0; ntd < 4; ++ntd) {
            const int vr = ntd * 16 + lr;
            vf[ntd][0] = *(const short8v*)&Vc[vr * 64 + ((quad ^ rsw) << 3)];
            vf[ntd][1] = *(const short8v*)&Vc[vr * 64 + (((quad + 4) ^ rsw) << 3)];
        }
        short8v pf[2][2];
#pragma unroll
        for (int mtq = 0; mtq < 2; ++mtq) {
            const int prow = w * 32 + mtq * 16 + lr;
            pf[mtq][0] = *(const short8v*)&QPs[prow * 64 + ((quad ^ rsw) << 3)];
            pf[mtq][1] = *(const short8v*)&QPs[prow * 64 + (((quad + 4) ^ rsw) << 3)];
        }
#pragma unroll
        for (int mtq = 0; mtq < 2; ++mtq)
#pragma unroll
            for (int ntd = 0; ntd < 4; ++ntd) {
                o_acc[mtq][ntd] = __builtin_amdgcn_mfma_f32_16x16x32_bf16(
                    pf[mtq][0], vf[ntd][0], o_acc[mtq][ntd], 0, 0, 0);
                o_acc[mtq][ntd] = __builtin_amdgcn_mfma_f32_16x16x32_bf16(
                    pf[mtq][1], vf[ntd][1], o_acc[mtq][ntd], 0, 0, 0);
            }
    }

    float rden[2];
#pragma unroll
    for (int ntq = 0; ntq < 2; ++ntq) {
        float t = lsum[ntq];
        t += __shfl_xor(t, 16);
        t += __shfl_xor(t, 32);
        rden[ntq] = 1.0f / t;
    }
#pragma unroll
    for (int mtq = 0; mtq < 2; ++mtq) {
#pragma unroll
        for (int reg = 0; reg < 4; ++reg) {
            const float dsc = __shfl(rden[mtq], quad * 4 + reg);
            const int m = row0 + w * 32 + mtq * 16 + quad * 4 + reg;
#pragma unroll
            for (int ntd = 0; ntd < 4; ++ntd)
                O[base + (size_t)m * 1024 + ntd * 16 + lr] =
                    f2bf(o_acc[mtq][ntd][reg] * dsc);
        }
    }
}

// ---------- fused partial-sum + bias + layernorm over 1024 cols ----------
__global__ __launch_bounds__(256) void lnf_k(
    const float* __restrict__ X, const float* __restrict__ P0,
    const float* __restrict__ P1, const float* __restrict__ cb,
    const float* __restrict__ g, const float* __restrict__ bb,
    float* __restrict__ outf, u16* __restrict__ outb) {
    const int row = blockIdx.x, tid = threadIdx.x;
    const size_t off = (size_t)row * 1024 + tid * 4;
    float4 xv = *(const float4*)&X[off];
    float4 p0 = *(const float4*)&P0[off];
    float4 p1 = *(const float4*)&P1[off];
    float4 c4 = *(const float4*)&cb[tid * 4];
    xv.x += p0.x + p1.x + c4.x;
    xv.y += p0.y + p1.y + c4.y;
    xv.z += p0.z + p1.z + c4.z;
    xv.w += p0.w + p1.w + c4.w;
    float s = xv.x + xv.y + xv.z + xv.w;
    float s2 = xv.x * xv.x + xv.y * xv.y + xv.z * xv.z + xv.w * xv.w;
#pragma unroll
    for (int msk = 32; msk >= 1; msk >>= 1) {
        s += __shfl_xor(s, msk);
        s2 += __shfl_xor(s2, msk);
    }
    __shared__ float red[8];
    const int wv = tid >> 6;
    if ((tid & 63) == 0) { red[wv] = s; red[wv + 4] = s2; }
    __syncthreads();
    s = red[0] + red[1] + red[2] + red[3];
    s2 = red[4] + red[5] + red[6] + red[7];
    const float mu = s * (1.f / 1024.f);
    float var = s2 * (1.f / 1024.f) - mu * mu;
    var = fmaxf(var, 0.f);
    const float rstd = rsqrtf(var + 1e-5f);
    float4 g4 = *(const float4*)&g[tid * 4];
    float4 b4 = *(const float4*)&bb[tid * 4];
    float o0 = (xv.x - mu) * rstd * g4.x + b4.x;
    float o1 = (xv.y - mu) * rstd * g4.y + b4.y;
    float o2 = (xv.z - mu) * rstd * g4.z + b4.z;
    float o3 = (xv.w - mu) * rstd * g4.w + b4.w;
    if (outf)
        *(float4*)(outf + off) = make_float4(o0, o1, o2, o3);
    if (outb) {
        ushort4 ov;
        ov.x = f2bf(o0); ov.y = f2bf(o1); ov.z = f2bf(o2); ov.w = f2bf(o3);
        *(ushort4*)(outb + off) = ov;
    }
}

extern "C" void kernel_launch(void* const* d_in, const int* in_sizes, int n_in,
                              void* d_out, int out_size, void* d_ws, size_t ws_size,
                              hipStream_t stream) {
    const float* tgt = (const float*)d_in[0];
    const float* Wq  = (const float*)d_in[1];
    const float* bq  = (const float*)d_in[2];
    const float* Wk  = (const float*)d_in[3];
    const float* bk  = (const float*)d_in[4];
    const float* Wv  = (const float*)d_in[5];
    const float* bv  = (const float*)d_in[6];
    const float* Wo  = (const float*)d_in[7];
    const float* bo  = (const float*)d_in[8];
    const float* W1  = (const float*)d_in[9];
    const float* b1  = (const float*)d_in[10];
    const float* W2  = (const float*)d_in[11];
    const float* b2  = (const float*)d_in[12];
    const float* g1  = (const float*)d_in[13];
    const float* be1 = (const float*)d_in[14];
    const float* g2  = (const float*)d_in[15];
    const float* be2 = (const float*)d_in[16];
    const float* rA  = (const float*)d_in[17];
    const float* rB  = (const float*)d_in[18];

    const int M = 4096, D = 1024, DFF = 4096;
    const size_t MD = (size_t)M * D;
    const size_t MB = 1u << 20;
    char* wsb = (char*)d_ws;

    // Lifetime-aliased layout (88 MB total) — unchanged from R10 (Pp removed).
    u16* q    = (u16*)wsb;
    u16* vv   = q + 2 * MD;
    u16* ctx  = (u16*)(wsb + 16 * MB);
    u16* Vt   = (u16*)(wsb + 24 * MB);
    u16* h    = q;
    float* PW0 = (float*)wsb;
    float* PW1 = (float*)(wsb + 32 * MB);
    float* PF0 = (float*)(wsb + 64 * MB);
    float* PF1 = (float*)(wsb + 32 * MB);
    float* sfp = (float*)(wsb + 32 * MB);
    float* cfp = sfp + (size_t)2048 * 512;
    u16* tgtb = (u16*)(wsb + 40 * MB);
    float* x1  = (float*)(wsb + 48 * MB);
    u16* x1b  = (u16*)(wsb + 64 * MB);
    u16* Wqt  = (u16*)(wsb + 64 * MB);
    u16* Wkt  = (u16*)(wsb + 66 * MB);
    u16* Wvt  = (u16*)(wsb + 68 * MB);
    u16* Wot  = (u16*)(wsb + 70 * MB);
    u16* W1t  = (u16*)(wsb + 72 * MB);
    u16* W2t  = (u16*)(wsb + 80 * MB);

    // fused prep: rope (self-contained P) + cast + 6 weight transposes
    prep_k<<<dim3(9216), dim3(256), 0, stream>>>(
        tgt, tgtb, Wq, Wqt, Wk, Wkt, Wv, Wvt, Wo, Wot,
        W1, W1t, W2, W2t, rA, rB, sfp, cfp);

    // QKV BN=128 (R6 best): 24n x 32m = 768 blocks (3/CU); xn=4 -> 6n x 16m/XCD
    mqkv_k<<<dim3(768), dim3(256), 0, stream>>>(
        tgtb, Wqt, bq, bk, bv, sfp, cfp, q);

    vtrans_k<<<dim3(64, 2, 32), dim3(256), 0, stream>>>(vv, Vt);

    // 512 blocks: 8 xcd x 4 bh x 16 row-tiles (128 q rows each)
    mattn_k<<<dim3(512), dim3(256), 0, stream>>>(q, q + MD, Vt, ctx);

    // Wo split-K x2, BN=128 (R6 best): 8n x (32m x 2kh) = 512 blocks, K=512
    mgemm_k<EP_PART, false, 128><<<dim3(512), dim3(256), 0, stream>>>(
        ctx, Wot, nullptr, PW0, PW1, M, D, 512, D, D, 1, 8, 8, 32);
    // lnf1: x_attn = tgt + PW0 + PW1 + bo -> LN -> x1 (fp32) + x1b (bf16)
    lnf_k<<<dim3(4096), dim3(256), 0, stream>>>(
        tgt, PW0, PW1, bo, g1, be1, x1, x1b);
    // FFN1: BN=128 -> 32n x 32m = 1024 blocks; xn=4 -> 8n x 16m per XCD
    mgemm_k<EP_RELU, true, 128><<<dim3(1024), dim3(256), 0, stream>>>(
        x1b, W1t, b1, h, nullptr, M, DFF, D, D, D, 4, 8, 16, 1 << 20);
    // FFN2 split-K x2, BN=64 (R8 best): 16n x (32m x 2kh) = 1024 blocks, K=2048
    mgemm_k<EP_PART, false, 64><<<dim3(1024), dim3(256), 0, stream>>>(
        h, W2t, nullptr, PF0, PF1, M, D, 2048, DFF, DFF, 2, 8, 16, 32);
    // lnf2: x_out = ln2(x1 + PF0 + PF1 + b2) -> d_out
    lnf_k<<<dim3(4096), dim3(256), 0, stream>>>(
        x1, PF0, PF1, b2, g2, be2, (float*)d_out, nullptr);

    (void)in_sizes; (void)n_in; (void)out_size; (void)ws_size;
}

// Round 12
// 394.870 us; speedup vs baseline: 1.1027x; 1.0200x over previous
//
#include <hip/hip_runtime.h>
#include <math.h>

typedef unsigned short u16;
typedef unsigned int u32;
typedef __attribute__((ext_vector_type(8))) short short8v;
typedef __attribute__((ext_vector_type(4))) float f32x4;

__device__ __forceinline__ u16 f2bf(float f) {
    u32 u = __float_as_uint(f);
    u32 r = (u + 0x7fffu + ((u >> 16) & 1u)) >> 16;
    return (u16)r;
}

// async global->LDS DMA, 16 B per lane; lds dst = wave-uniform base + lane*16
#define GLOAD_LDS(g, l)                                                        \
    __builtin_amdgcn_global_load_lds(                                          \
        (const __attribute__((address_space(1))) void*)(g),                    \
        (__attribute__((address_space(3))) void*)(l), 16, 0, 0)

#define SCHED_FENCE() __builtin_amdgcn_sched_barrier(0)

// log2(10000)/512
#define ROPE_LOG2C (13.287712379549449f / 512.0f)

// ================= fused prep kernel =================
// One launch replacing {rope1, rope2, cast, tcast x6}. The rope role is
// self-contained: each block (one t) recomputes P[t][0..16) itself
// (67 MFLOP total chip-wide) -> no intra-launch ordering dependency.
__device__ __forceinline__ void cast_body(const float* __restrict__ x,
                                          u16* __restrict__ y, int L, int tid) {
    const int gid = L * 256 + tid;
    float4 v = ((const float4*)x)[gid];
    ushort4 o;
    o.x = f2bf(v.x); o.y = f2bf(v.y); o.z = f2bf(v.z); o.w = f2bf(v.w);
    ((ushort4*)y)[gid] = o;
}

__device__ __forceinline__ void tcast64_body(const float* __restrict__ S,
                                             u16* __restrict__ Dt, int K, int N,
                                             int n0, int k0, int tid,
                                             char* smem) {
    float (*tile)[65] = (float (*)[65])smem;
    const int tx = tid & 15, ty = tid >> 4;
#pragma unroll
    for (int i = 0; i < 4; i++) {
        const int kr = ty + 16 * i;
        const float4 v = *(const float4*)&S[(size_t)(k0 + kr) * N + n0 + tx * 4];
        tile[kr][tx * 4 + 0] = v.x;
        tile[kr][tx * 4 + 1] = v.y;
        tile[kr][tx * 4 + 2] = v.z;
        tile[kr][tx * 4 + 3] = v.w;
    }
    __syncthreads();
#pragma unroll
    for (int i = 0; i < 4; i++) {
        const int nr = ty + 16 * i;
        ushort4 o;
        o.x = f2bf(tile[tx * 4 + 0][nr]);
        o.y = f2bf(tile[tx * 4 + 1][nr]);
        o.z = f2bf(tile[tx * 4 + 2][nr]);
        o.w = f2bf(tile[tx * 4 + 3][nr]);
        *(ushort4*)&Dt[(size_t)(n0 + nr) * K + k0 + tx * 4] = o;
    }
}

// rope role: one block per t. P[t][r] = sum_j base[t][j]*rA[j][r] computed
// in-block (thread owns 4 j's), tree-reduced; then sf/cf elementwise.
__device__ __forceinline__ void ropef_body(const float* __restrict__ rA,
                                           const float* __restrict__ Bw,
                                           float* __restrict__ sf,
                                           float* __restrict__ cf,
                                           int t, int tid, char* smem) {
    float* red = (float*)smem;   // [4][16] wave sums, [64..80) final P
    float p[16];
#pragma unroll
    for (int r = 0; r < 16; ++r) p[r] = 0.f;
#pragma unroll
    for (int jj = 0; jj < 4; ++jj) {
        const int j = tid * 4 + jj;
        const int i = (j < 512) ? j : (j - 512);
        const float th = exp2f(-(float)i * ROPE_LOG2C);
        const float ang = (float)t * th;
        const float base = (j < 512) ? sinf(ang) : cosf(ang);
        const float4* arow = (const float4*)&rA[j * 16];
        const float4 a0 = arow[0], a1 = arow[1], a2 = arow[2], a3 = arow[3];
        p[0] = fmaf(base, a0.x, p[0]);  p[1] = fmaf(base, a0.y, p[1]);
        p[2] = fmaf(base, a0.z, p[2]);  p[3] = fmaf(base, a0.w, p[3]);
        p[4] = fmaf(base, a1.x, p[4]);  p[5] = fmaf(base, a1.y, p[5]);
        p[6] = fmaf(base, a1.z, p[6]);  p[7] = fmaf(base, a1.w, p[7]);
        p[8] = fmaf(base, a2.x, p[8]);  p[9] = fmaf(base, a2.y, p[9]);
        p[10] = fmaf(base, a2.z, p[10]); p[11] = fmaf(base, a2.w, p[11]);
        p[12] = fmaf(base, a3.x, p[12]); p[13] = fmaf(base, a3.y, p[13]);
        p[14] = fmaf(base, a3.z, p[14]); p[15] = fmaf(base, a3.w, p[15]);
    }
    const int w = tid >> 6, lane = tid & 63;
#pragma unroll
    for (int r = 0; r < 16; ++r) {
        float v = p[r];
        v += __shfl_xor(v, 1);  v += __shfl_xor(v, 2);
        v += __shfl_xor(v, 4);  v += __shfl_xor(v, 8);
        v += __shfl_xor(v, 16); v += __shfl_xor(v, 32);
        if (lane == 0) red[w * 16 + r] = v;
    }
    __syncthreads();
    if (tid < 16)
        red[64 + tid] = red[tid] + red[16 + tid] + red[32 + tid] + red[48 + tid];
    __syncthreads();
#pragma unroll
    for (int half = 0; half < 2; ++half) {
        const int i = tid + half * 256;
        float ls = 0.f, lc = 0.f;
#pragma unroll
        for (int r = 0; r < 16; ++r) {
            const float Pr = red[64 + r];
            ls = fmaf(Pr, Bw[r * 1024 + i], ls);
            lc = fmaf(Pr, Bw[r * 1024 + 512 + i], lc);
        }
        const float th = exp2f(-(float)i * ROPE_LOG2C);
        const float ang = (float)t * th;
        sf[t * 512 + i] = sinf(ang) + ls;
        cf[t * 512 + i] = cosf(ang) + lc;
    }
}

__global__ __launch_bounds__(256) void prep_k(
    const float* __restrict__ tgt, u16* __restrict__ tgtb,
    const float* __restrict__ Wq, u16* __restrict__ Wqt,
    const float* __restrict__ Wk, u16* __restrict__ Wkt,
    const float* __restrict__ Wv, u16* __restrict__ Wvt,
    const float* __restrict__ Wo, u16* __restrict__ Wot,
    const float* __restrict__ W1, u16* __restrict__ W1t,
    const float* __restrict__ W2, u16* __restrict__ W2t,
    const float* __restrict__ rA, const float* __restrict__ Bw,
    float* __restrict__ sf, float* __restrict__ cf) {
    __shared__ char smem[64 * 65 * 4];
    const int L = blockIdx.x, tid = threadIdx.x;
    if (L < 2048) {                                    // rope (self-contained)
        ropef_body(rA, Bw, sf, cf, L, tid, smem);
    } else if (L < 6144) {                             // cast tgt -> bf16
        cast_body(tgt, tgtb, L - 2048, tid);
    } else if (L < 7168) {                             // 4x 1024^2 transpose
        const int i = L - 6144;
        const int r = i >> 8, j = i & 255;
        const float* S = r == 0 ? Wq : (r == 1 ? Wk : (r == 2 ? Wv : Wo));
        u16* Dt = r == 0 ? Wqt : (r == 1 ? Wkt : (r == 2 ? Wvt : Wot));
        tcast64_body(S, Dt, 1024, 1024, (j & 15) * 64, (j >> 4) * 64, tid, smem);
    } else if (L < 8192) {                             // W1 (1024x4096)
        const int j = L - 7168;
        tcast64_body(W1, W1t, 1024, 4096, (j & 63) * 64, (j >> 6) * 64, tid, smem);
    } else {                                           // W2 (4096x1024)
        const int j = L - 8192;
        tcast64_body(W2, W2t, 4096, 1024, (j & 15) * 64, (j >> 4) * 64, tid, smem);
    }
}

// XCD supertile mapping: linear grid; xcd = L&7 owns an rn x rm tile region.
__device__ __forceinline__ void xcd_tile(int L, int xn, int rn, int rm,
                                         int& tm, int& tn) {
    const int xcd = L & 7, i = L >> 3;
    const int cx = xcd % xn, cy = xcd / xn;
    tn = cx * rn + (i % rn);
    tm = cy * rm + (i / rn);
}

// ---------- MFMA GEMM (128xBN, 4 waves): 3-stage DMA pipeline ----
// Split-K: tm >= mtiles selects K-half kh=1 (A/Bt advance kh*K columns;
// fp32 partial written to Cp2). lda/ldb are full row strides.
enum { EP_NONE = 0, EP_RELU = 3, EP_PART = 4 };

template <int EPI, bool CBF, int BN>
__global__ __launch_bounds__(256) void mgemm_k(
    const u16* __restrict__ A, const u16* __restrict__ Bt,
    const float* __restrict__ bias, void* __restrict__ Cp,
    void* __restrict__ Cp2, int M, int N, int K, int lda, int ldb,
    int xn, int rn, int rm, int mtiles) {
    constexpr int NT = BN / 32;            // n-frags per wave
    __shared__ u16 As[3 * 128 * 32];
    __shared__ u16 Bs[3 * BN * 32];
    const int tid = threadIdx.x;
    const int w = tid >> 6, l = tid & 63;
    const int quad = l >> 4, lr = l & 15;
    const int wr = w >> 1, wc = w & 1;
    int tm, tn;
    xcd_tile(blockIdx.x, xn, rn, rm, tm, tn);
    int kh = 0;
    if (tm >= mtiles) { kh = 1; tm -= mtiles; }
    const u16* Ak = A + (size_t)kh * K;
    const u16* Bk = Bt + (size_t)kh * K;
    void* Co = kh ? Cp2 : Cp;
    const int m0 = tm * 128, n0 = tn * BN;

    const int srow = w * 16 + (l >> 2);    // staging row (64-row round)
    const int scol = (((l & 3) ^ ((l >> 3) & 3)) * 8);
    const u16* ag0 = Ak + (size_t)(m0 + srow) * lda + scol;
    const u16* ag1 = Ak + (size_t)(m0 + 64 + srow) * lda + scol;
    const u16* bg0 = Bk + (size_t)(n0 + srow) * ldb + scol;
    const u16* bg1 = Bk + (size_t)(n0 + 64 + srow) * ldb + scol;  // BN==128 only

    f32x4 acc[4][NT];
#pragma unroll
    for (int i = 0; i < 4; i++)
#pragma unroll
        for (int j = 0; j < NT; j++) acc[i][j] = (f32x4)(0.0f);

    // prologue: stage tiles 0,1 into buffers 0,1 (issue order = tile order)
    {
        GLOAD_LDS(ag0, As + w * 512);
        GLOAD_LDS(ag1, As + 2048 + w * 512);
        GLOAD_LDS(bg0, Bs + w * 512);
        if (BN == 128) GLOAD_LDS(bg1, Bs + 2048 + w * 512);
        GLOAD_LDS(ag0 + 32, As + 4096 + w * 512);
        GLOAD_LDS(ag1 + 32, As + 4096 + 2048 + w * 512);
        GLOAD_LDS(bg0 + 32, Bs + BN * 32 + w * 512);
        if (BN == 128) GLOAD_LDS(bg1 + 32, Bs + BN * 32 + 2048 + w * 512);
    }

    const int niter = K >> 5;
    const int xsw = ((lr >> 1) & 3) << 3;  // read-side granule XOR (u16 units)
    int bc = 0, bs = 2;                    // compute buf, stage buf (i+2)%3
    for (int i = 0; i < niter; ++i) {
        SCHED_FENCE();
        if (i + 1 < niter) {
            if (BN == 128) asm volatile("s_waitcnt vmcnt(4) lgkmcnt(0)" ::: "memory");
            else           asm volatile("s_waitcnt vmcnt(3) lgkmcnt(0)" ::: "memory");
        } else {
            asm volatile("s_waitcnt vmcnt(0) lgkmcnt(0)" ::: "memory");
        }
        __builtin_amdgcn_s_barrier();
        SCHED_FENCE();
        if (i + 2 < niter) {
            const int kk = (i + 2) << 5;
            u16* Ab = As + bs * 4096;
            u16* Bb = Bs + bs * (BN * 32);
            GLOAD_LDS(ag0 + kk, Ab + w * 512);
            GLOAD_LDS(ag1 + kk, Ab + 2048 + w * 512);
            GLOAD_LDS(bg0 + kk, Bb + w * 512);
            if (BN == 128) GLOAD_LDS(bg1 + kk, Bb + 2048 + w * 512);
        }
        const u16* Ac = As + bc * 4096;
        const u16* Bc = Bs + bc * (BN * 32);
        short8v af[4], bf[NT];
#pragma unroll
        for (int mt = 0; mt < 4; ++mt)
            af[mt] = *(const short8v*)&Ac[(wr * 64 + mt * 16 + lr) * 32 +
                                          ((quad << 3) ^ xsw)];
#pragma unroll
        for (int nt = 0; nt < NT; ++nt)
            bf[nt] = *(const short8v*)&Bc[(wc * (BN / 2) + nt * 16 + lr) * 32 +
                                          ((quad << 3) ^ xsw)];
#pragma unroll
        for (int mt = 0; mt < 4; ++mt)
#pragma unroll
            for (int nt = 0; nt < NT; ++nt)
                acc[mt][nt] = __builtin_amdgcn_mfma_f32_16x16x32_bf16(
                    af[mt], bf[nt], acc[mt][nt], 0, 0, 0);
        bc = (bc == 2) ? 0 : bc + 1;
        bs = (bs == 2) ? 0 : bs + 1;
    }

#pragma unroll
    for (int mt = 0; mt < 4; ++mt) {
#pragma unroll
        for (int nt = 0; nt < NT; ++nt) {
            const int n = n0 + wc * (BN / 2) + nt * 16 + lr;
            const float bb = (EPI == EP_PART) ? 0.0f : bias[n];
#pragma unroll
            for (int reg = 0; reg < 4; ++reg) {
                const int m = m0 + wr * 64 + mt * 16 + quad * 4 + reg;
                float v = acc[mt][nt][reg] + bb;
                if (EPI == EP_RELU) v = fmaxf(v, 0.f);
                if (CBF) ((u16*)Co)[(size_t)m * N + n] = f2bf(v);
                else     ((float*)Co)[(size_t)m * N + n] = v;
            }
        }
    }
}

// ---------- merged QKV GEMM (N=3072), BN=128, 3-stage pipeline, RoPE ----
// V band (which==2) writes DIRECTLY to Vt[bh][d][key_swz] (vtrans folded in):
// a lane's 4 regs = 4 consecutive keys at fixed d -> one aligned ushort4.
__global__ __launch_bounds__(256) void mqkv_k(
    const u16* __restrict__ A, const u16* __restrict__ Bt,
    const float* __restrict__ bq, const float* __restrict__ bk,
    const float* __restrict__ bv, const float* __restrict__ sf,
    const float* __restrict__ cf, u16* __restrict__ out,
    u16* __restrict__ Vt) {
    const int K = 1024;
    __shared__ u16 As[3 * 128 * 32];
    __shared__ u16 Bs[3 * 128 * 32];
    const int tid = threadIdx.x;
    const int w = tid >> 6, l = tid & 63;
    const int quad = l >> 4, lr = l & 15;
    const int wr = w >> 1, wc = w & 1;
    int tm, tn;
    xcd_tile(blockIdx.x, 4, 6, 16, tm, tn);   // 24n x 32m grid
    const int m0 = tm * 128, n0 = tn * 128;

    const int srow = w * 16 + (l >> 2);
    const int scol = (((l & 3) ^ ((l >> 3) & 3)) * 8);
    const u16* ag0 = A + (size_t)(m0 + srow) * K + scol;
    const u16* ag1 = A + (size_t)(m0 + 64 + srow) * K + scol;
    const u16* bg0 = Bt + (size_t)(n0 + srow) * K + scol;
    const u16* bg1 = Bt + (size_t)(n0 + 64 + srow) * K + scol;

    f32x4 acc[4][4];
#pragma unroll
    for (int i = 0; i < 4; i++)
#pragma unroll
        for (int j = 0; j < 4; j++) acc[i][j] = (f32x4)(0.0f);

    {
        GLOAD_LDS(ag0, As + w * 512);
        GLOAD_LDS(ag1, As + 2048 + w * 512);
        GLOAD_LDS(bg0, Bs + w * 512);
        GLOAD_LDS(bg1, Bs + 2048 + w * 512);
        GLOAD_LDS(ag0 + 32, As + 4096 + w * 512);
        GLOAD_LDS(ag1 + 32, As + 4096 + 2048 + w * 512);
        GLOAD_LDS(bg0 + 32, Bs + 4096 + w * 512);
        GLOAD_LDS(bg1 + 32, Bs + 4096 + 2048 + w * 512);
    }
    const int xsw = ((lr >> 1) & 3) << 3;
    int bc = 0, bsb = 2;
    for (int i = 0; i < 32; ++i) {
        SCHED_FENCE();
        if (i + 1 < 32) {
            asm volatile("s_waitcnt vmcnt(4) lgkmcnt(0)" ::: "memory");
        } else {
            asm volatile("s_waitcnt vmcnt(0) lgkmcnt(0)" ::: "memory");
        }
        __builtin_amdgcn_s_barrier();
        SCHED_FENCE();
        if (i + 2 < 32) {
            const int kk = (i + 2) << 5;
            u16* Ab = As + bsb * 4096;
            u16* Bb = Bs + bsb * 4096;
            GLOAD_LDS(ag0 + kk, Ab + w * 512);
            GLOAD_LDS(ag1 + kk, Ab + 2048 + w * 512);
            GLOAD_LDS(bg0 + kk, Bb + w * 512);
            GLOAD_LDS(bg1 + kk, Bb + 2048 + w * 512);
        }
        const u16* Ac = As + bc * 4096;
        const u16* Bc = Bs + bc * 4096;
        short8v af[4], bf[4];
#pragma unroll
        for (int mt = 0; mt < 4; ++mt)
            af[mt] = *(const short8v*)&Ac[(wr * 64 + mt * 16 + lr) * 32 +
                                          ((quad << 3) ^ xsw)];
#pragma unroll
        for (int nt = 0; nt < 4; ++nt)
            bf[nt] = *(const short8v*)&Bc[(wc * 64 + nt * 16 + lr) * 32 +
                                          ((quad << 3) ^ xsw)];
#pragma unroll
        for (int mt = 0; mt < 4; ++mt)
#pragma unroll
            for (int nt = 0; nt < 4; ++nt)
                acc[mt][nt] = __builtin_amdgcn_mfma_f32_16x16x32_bf16(
                    af[mt], bf[nt], acc[mt][nt], 0, 0, 0);
        bc = (bc == 2) ? 0 : bc + 1;
        bsb = (bsb == 2) ? 0 : bsb + 1;
    }

    const int which = n0 >> 10;  // block-uniform (1024-boundaries align)
    const float* bias = which == 0 ? bq : (which == 1 ? bk : bv);
    u16* Cp = out + (size_t)which * 4096 * 1024;

    if (which == 2) {
        // V band: direct transposed+swizzled store to Vt[bh*64+d][2048]
#pragma unroll
        for (int mt = 0; mt < 4; ++mt) {
#pragma unroll
            for (int nt = 0; nt < 4; ++nt) {
                const int col = (n0 + wc * 64 + nt * 16 + lr) & 1023;
                const int hh = col >> 6, d = col & 63;
                const float bb = bias[col];
                const int mb = m0 + wr * 64 + mt * 16 + quad * 4;  // reg base
                const int b = mb >> 11;
                const int keyb = mb & 2047;                        // +reg
                // granule swizzle constant across reg (quad*4..quad*4+3
                // stay inside one 8-key granule)
                const int ksw = (keyb & ~63) |
                                ((((keyb >> 3) & 7) ^ (d & 7)) << 3) |
                                (keyb & 7);
                ushort4 o;
                o.x = f2bf(acc[mt][nt][0] + bb);
                o.y = f2bf(acc[mt][nt][1] + bb);
                o.z = f2bf(acc[mt][nt][2] + bb);
                o.w = f2bf(acc[mt][nt][3] + bb);
                *(ushort4*)&Vt[((size_t)(b * 16 + hh) * 64 + d) * 2048 + ksw] = o;
            }
        }
    } else {
#pragma unroll
        for (int mt = 0; mt < 4; ++mt) {
#pragma unroll
            for (int nt = 0; nt < 4; ++nt) {
                const int n = n0 + wc * 64 + nt * 16 + lr;
                const int col = n & 1023;
                const float bb = bias[col];
#pragma unroll
                for (int reg = 0; reg < 4; ++reg) {
                    const int m = m0 + wr * 64 + mt * 16 + quad * 4 + reg;
                    float v = acc[mt][nt][reg] + bb;
                    const float partner = __shfl_xor(v, 1);
                    const int t = m & 2047;
                    const int fi = col >> 1;
                    const float svv = sf[t * 512 + fi];
                    const float cvv = cf[t * 512 + fi];
                    v = (col & 1) ? fmaf(partner, svv, v * cvv)
                                  : fmaf(v, cvv, -partner * svv);
                    if (which == 0) v *= 0.125f;
                    const int colw = (col & ~63) |
                                     ((((col >> 3) & 7) ^ (m & 7)) << 3) |
                                     (col & 7);
                    Cp[(size_t)m * 1024 + colw] = f2bf(v);
                }
            }
        }
    }
}

// ---------- MFMA flash attention v2 ----------
// 512 blocks, 4 waves, 128 q-rows/block (32/wave), KVBLK=64 double-buffered.
__global__ __launch_bounds__(256, 3) void mattn_k(
    const u16* __restrict__ Q, const u16* __restrict__ Kg,
    const u16* __restrict__ Vt, u16* __restrict__ O) {
    __shared__ u16 QPs[128 * 64];     // Q staging (prologue), then P tiles
    __shared__ u16 Ks[2][64 * 64];
    __shared__ u16 Vs[2][64 * 64];
    const int tid = threadIdx.x;
    const int w = tid >> 6, l = tid & 63;
    const int quad = l >> 4, lr = l & 15;
    const int L = blockIdx.x;                      // 512 blocks
    const int bh = (L & 7) * 4 + ((L >> 3) & 3);   // 4 bh per XCD (L2 locality)
    const int b = bh >> 4, h = bh & 15;
    const int row0 = (L >> 5) * 128;
    const size_t base = (size_t)b * 2048 * 1024 + (size_t)h * 64;
    const size_t vbase = (size_t)bh * 64 * 2048;

    const int dr = l >> 3;
    const int dc = (l & 7) * 8;
    const int g0 = w * 2, g1 = g0 + 1;
    const u16* kg0 = Kg + base + (size_t)(g0 * 8 + dr) * 1024 + dc;
    const u16* kg1 = Kg + base + (size_t)(g1 * 8 + dr) * 1024 + dc;
    const u16* vg0 = Vt + vbase + (size_t)(g0 * 8 + dr) * 2048 + dc;
    const u16* vg1 = Vt + vbase + (size_t)(g1 * 8 + dr) * 2048 + dc;

#pragma unroll
    for (int j = 0; j < 4; ++j) {
        const int g = w * 4 + j;
        GLOAD_LDS(Q + base + (size_t)(row0 + g * 8 + dr) * 1024 + dc,
                  QPs + g * 512);
    }
    GLOAD_LDS(kg0, Ks[0] + g0 * 512);
    GLOAD_LDS(kg1, Ks[0] + g1 * 512);
    GLOAD_LDS(vg0, Vs[0] + g0 * 512);
    GLOAD_LDS(vg1, Vs[0] + g1 * 512);
    __syncthreads();

    const int rsw = lr & 7;
    short8v qf[2][2];
#pragma unroll
    for (int ntq = 0; ntq < 2; ++ntq) {
        const int qr = w * 32 + ntq * 16 + lr;
#pragma unroll
        for (int kh = 0; kh < 2; ++kh)
            qf[ntq][kh] = *(const short8v*)&QPs[qr * 64 +
                (((kh * 4 + quad) ^ rsw) << 3)];
    }

    f32x4 o_acc[2][4];
#pragma unroll
    for (int i = 0; i < 2; ++i)
#pragma unroll
        for (int j = 0; j < 4; ++j) o_acc[i][j] = (f32x4)(0.0f);
    float lsum[2] = {0.f, 0.f};

    for (int i = 0; i < 32; ++i) {
        __syncthreads();
        if (i + 1 < 32) {
            const size_t kro = (size_t)((i + 1) << 6) * 1024;
            const int kco = (i + 1) << 6;
            u16* Kb = Ks[(i + 1) & 1];
            u16* Vb = Vs[(i + 1) & 1];
            GLOAD_LDS(kg0 + kro, Kb + g0 * 512);
            GLOAD_LDS(kg1 + kro, Kb + g1 * 512);
            GLOAD_LDS(vg0 + kco, Vb + g0 * 512);
            GLOAD_LDS(vg1 + kco, Vb + g1 * 512);
        }
        const u16* Kc = Ks[i & 1];
        const u16* Vc = Vs[i & 1];

        f32x4 s[4][2];
#pragma unroll
        for (int mt = 0; mt < 4; ++mt)
#pragma unroll
            for (int ntq = 0; ntq < 2; ++ntq) s[mt][ntq] = (f32x4)(0.0f);
#pragma unroll
        for (int mt = 0; mt < 4; ++mt) {
            const int kr = mt * 16 + lr;
            const short8v kf0 = *(const short8v*)&Kc[kr * 64 + ((quad ^ rsw) << 3)];
            const short8v kf1 = *(const short8v*)&Kc[kr * 64 + (((quad + 4) ^ rsw) << 3)];
#pragma unroll
            for (int ntq = 0; ntq < 2; ++ntq) {
                s[mt][ntq] = __builtin_amdgcn_mfma_f32_16x16x32_bf16(
                    kf0, qf[ntq][0], s[mt][ntq], 0, 0, 0);
                s[mt][ntq] = __builtin_amdgcn_mfma_f32_16x16x32_bf16(
                    kf1, qf[ntq][1], s[mt][ntq], 0, 0, 0);
            }
        }

#pragma unroll
        for (int ntq = 0; ntq < 2; ++ntq) {
            const int prow = w * 32 + ntq * 16 + lr;
#pragma unroll
            for (int mt = 0; mt < 4; ++mt) {
                const float e0 = __expf(s[mt][ntq][0]);
                const float e1 = __expf(s[mt][ntq][1]);
                const float e2 = __expf(s[mt][ntq][2]);
                const float e3 = __expf(s[mt][ntq][3]);
                lsum[ntq] += (e0 + e1) + (e2 + e3);
                u32 p01, p23;
                asm("v_cvt_pk_bf16_f32 %0, %1, %2" : "=v"(p01) : "v"(e0), "v"(e1));
                asm("v_cvt_pk_bf16_f32 %0, %1, %2" : "=v"(p23) : "v"(e2), "v"(e3));
                uint2 pv; pv.x = p01; pv.y = p23;
                *(uint2*)&QPs[prow * 64 +
                              (((mt * 2 + (quad >> 1)) ^ rsw) << 3) +
                              (quad & 1) * 4] = pv;
            }
        }

        short8v vf[4][2];
#pragma unroll
        for (int ntd = 0; ntd < 4; ++ntd) {
            const int vr = ntd * 16 + lr;
            vf[ntd][0] = *(const short8v*)&Vc[vr * 64 + ((quad ^ rsw) << 3)];
            vf[ntd][1] = *(const short8v*)&Vc[vr * 64 + (((quad + 4) ^ rsw) << 3)];
        }
        short8v pf[2][2];
#pragma unroll
        for (int mtq = 0; mtq < 2; ++mtq) {
            const int prow = w * 32 + mtq * 16 + lr;
            pf[mtq][0] = *(const short8v*)&QPs[prow * 64 + ((quad ^ rsw) << 3)];
            pf[mtq][1] = *(const short8v*)&QPs[prow * 64 + (((quad + 4) ^ rsw) << 3)];
        }
#pragma unroll
        for (int mtq = 0; mtq < 2; ++mtq)
#pragma unroll
            for (int ntd = 0; ntd < 4; ++ntd) {
                o_acc[mtq][ntd] = __builtin_amdgcn_mfma_f32_16x16x32_bf16(
                    pf[mtq][0], vf[ntd][0], o_acc[mtq][ntd], 0, 0, 0);
                o_acc[mtq][ntd] = __builtin_amdgcn_mfma_f32_16x16x32_bf16(
                    pf[mtq][1], vf[ntd][1], o_acc[mtq][ntd], 0, 0, 0);
            }
    }

    float rden[2];
#pragma unroll
    for (int ntq = 0; ntq < 2; ++ntq) {
        float t = lsum[ntq];
        t += __shfl_xor(t, 16);
        t += __shfl_xor(t, 32);
        rden[ntq] = 1.0f / t;
    }
#pragma unroll
    for (int mtq = 0; mtq < 2; ++mtq) {
#pragma unroll
        for (int reg = 0; reg < 4; ++reg) {
            const float dsc = __shfl(rden[mtq], quad * 4 + reg);
            const int m = row0 + w * 32 + mtq * 16 + quad * 4 + reg;
#pragma unroll
            for (int ntd = 0; ntd < 4; ++ntd)
                O[base + (size_t)m * 1024 + ntd * 16 + lr] =
                    f2bf(o_acc[mtq][ntd][reg] * dsc);
        }
    }
}

// ---------- fused partial-sum + bias + layernorm over 1024 cols ----------
__global__ __launch_bounds__(256) void lnf_k(
    const float* __restrict__ X, const float* __restrict__ P0,
    const float* __restrict__ P1, const float* __restrict__ cb,
    const float* __restrict__ g, const float* __restrict__ bb,
    float* __restrict__ outf, u16* __restrict__ outb) {
    const int row = blockIdx.x, tid = threadIdx.x;
    const size_t off = (size_t)row * 1024 + tid * 4;
    float4 xv = *(const float4*)&X[off];
    float4 p0 = *(const float4*)&P0[off];
    float4 p1 = *(const float4*)&P1[off];
    float4 c4 = *(const float4*)&cb[tid * 4];
    xv.x += p0.x + p1.x + c4.x;
    xv.y += p0.y + p1.y + c4.y;
    xv.z += p0.z + p1.z + c4.z;
    xv.w += p0.w + p1.w + c4.w;
    float s = xv.x + xv.y + xv.z + xv.w;
    float s2 = xv.x * xv.x + xv.y * xv.y + xv.z * xv.z + xv.w * xv.w;
#pragma unroll
    for (int msk = 32; msk >= 1; msk >>= 1) {
        s += __shfl_xor(s, msk);
        s2 += __shfl_xor(s2, msk);
    }
    __shared__ float red[8];
    const int wv = tid >> 6;
    if ((tid & 63) == 0) { red[wv] = s; red[wv + 4] = s2; }
    __syncthreads();
    s = red[0] + red[1] + red[2] + red[3];
    s2 = red[4] + red[5] + red[6] + red[7];
    const float mu = s * (1.f / 1024.f);
    float var = s2 * (1.f / 1024.f) - mu * mu;
    var = fmaxf(var, 0.f);
    const float rstd = rsqrtf(var + 1e-5f);
    float4 g4 = *(const float4*)&g[tid * 4];
    float4 b4 = *(const float4*)&bb[tid * 4];
    float o0 = (xv.x - mu) * rstd * g4.x + b4.x;
    float o1 = (xv.y - mu) * rstd * g4.y + b4.y;
    float o2 = (xv.z - mu) * rstd * g4.z + b4.z;
    float o3 = (xv.w - mu) * rstd * g4.w + b4.w;
    if (outf)
        *(float4*)(outf + off) = make_float4(o0, o1, o2, o3);
    if (outb) {
        ushort4 ov;
        ov.x = f2bf(o0); ov.y = f2bf(o1); ov.z = f2bf(o2); ov.w = f2bf(o3);
        *(ushort4*)(outb + off) = ov;
    }
}

extern "C" void kernel_launch(void* const* d_in, const int* in_sizes, int n_in,
                              void* d_out, int out_size, void* d_ws, size_t ws_size,
                              hipStream_t stream) {
    const float* tgt = (const float*)d_in[0];
    const float* Wq  = (const float*)d_in[1];
    const float* bq  = (const float*)d_in[2];
    const float* Wk  = (const float*)d_in[3];
    const float* bk  = (const float*)d_in[4];
    const float* Wv  = (const float*)d_in[5];
    const float* bv  = (const float*)d_in[6];
    const float* Wo  = (const float*)d_in[7];
    const float* bo  = (const float*)d_in[8];
    const float* W1  = (const float*)d_in[9];
    const float* b1  = (const float*)d_in[10];
    const float* W2  = (const float*)d_in[11];
    const float* b2  = (const float*)d_in[12];
    const float* g1  = (const float*)d_in[13];
    const float* be1 = (const float*)d_in[14];
    const float* g2  = (const float*)d_in[15];
    const float* be2 = (const float*)d_in[16];
    const float* rA  = (const float*)d_in[17];
    const float* rB  = (const float*)d_in[18];

    const int M = 4096, D = 1024, DFF = 4096;
    const size_t MD = (size_t)M * D;
    const size_t MB = 1u << 20;
    char* wsb = (char*)d_ws;

    // Lifetime-aliased layout (88 MB total); vv eliminated (V goes straight
    // to Vt from mqkv).
    u16* q    = (u16*)wsb;
    u16* ctx  = (u16*)(wsb + 16 * MB);
    u16* Vt   = (u16*)(wsb + 24 * MB);
    u16* h    = q;
    float* PW0 = (float*)wsb;
    float* PW1 = (float*)(wsb + 32 * MB);
    float* PF0 = (float*)(wsb + 64 * MB);
    float* PF1 = (float*)(wsb + 32 * MB);
    float* sfp = (float*)(wsb + 32 * MB);
    float* cfp = sfp + (size_t)2048 * 512;
    u16* tgtb = (u16*)(wsb + 40 * MB);
    float* x1  = (float*)(wsb + 48 * MB);
    u16* x1b  = (u16*)(wsb + 64 * MB);
    u16* Wqt  = (u16*)(wsb + 64 * MB);
    u16* Wkt  = (u16*)(wsb + 66 * MB);
    u16* Wvt  = (u16*)(wsb + 68 * MB);
    u16* Wot  = (u16*)(wsb + 70 * MB);
    u16* W1t  = (u16*)(wsb + 72 * MB);
    u16* W2t  = (u16*)(wsb + 80 * MB);

    // fused prep: rope (self-contained P) + cast + 6 weight transposes
    prep_k<<<dim3(9216), dim3(256), 0, stream>>>(
        tgt, tgtb, Wq, Wqt, Wk, Wkt, Wv, Wvt, Wo, Wot,
        W1, W1t, W2, W2t, rA, rB, sfp, cfp);

    // QKV BN=128: 24n x 32m = 768 blocks (3/CU); V written directly to Vt
    mqkv_k<<<dim3(768), dim3(256), 0, stream>>>(
        tgtb, Wqt, bq, bk, bv, sfp, cfp, q, Vt);

    // 512 blocks: 8 xcd x 4 bh x 16 row-tiles (128 q rows each)
    mattn_k<<<dim3(512), dim3(256), 0, stream>>>(q, q + MD, Vt, ctx);

    // Wo split-K x2, BN=128 (R6 best): 8n x (32m x 2kh) = 512 blocks, K=512
    mgemm_k<EP_PART, false, 128><<<dim3(512), dim3(256), 0, stream>>>(
        ctx, Wot, nullptr, PW0, PW1, M, D, 512, D, D, 1, 8, 8, 32);
    // lnf1: x_attn = tgt + PW0 + PW1 + bo -> LN -> x1 (fp32) + x1b (bf16)
    lnf_k<<<dim3(4096), dim3(256), 0, stream>>>(
        tgt, PW0, PW1, bo, g1, be1, x1, x1b);
    // FFN1: BN=128 -> 32n x 32m = 1024 blocks; xn=4 -> 8n x 16m per XCD
    mgemm_k<EP_RELU, true, 128><<<dim3(1024), dim3(256), 0, stream>>>(
        x1b, W1t, b1, h, nullptr, M, DFF, D, D, D, 4, 8, 16, 1 << 20);
    // FFN2 split-K x2, BN=64 (R8 best): 16n x (32m x 2kh) = 1024 blocks, K=2048
    mgemm_k<EP_PART, false, 64><<<dim3(1024), dim3(256), 0, stream>>>(
        h, W2t, nullptr, PF0, PF1, M, D, 2048, DFF, DFF, 2, 8, 16, 32);
    // lnf2: x_out = ln2(x1 + PF0 + PF1 + b2) -> d_out
    lnf_k<<<dim3(4096), dim3(256), 0, stream>>>(
        x1, PF0, PF1, b2, g2, be2, (float*)d_out, nullptr);

    (void)in_sizes; (void)n_in; (void)out_size; (void)ws_size;
}

// Round 13
// 380.741 us; speedup vs baseline: 1.1436x; 1.0371x over previous
//
#include <hip/hip_runtime.h>
#include <math.h>

typedef unsigned short u16;
typedef unsigned int u32;
typedef __attribute__((ext_vector_type(8))) short short8v;
typedef __attribute__((ext_vector_type(4))) float f32x4;

__device__ __forceinline__ u16 f2bf(float f) {
    u32 u = __float_as_uint(f);
    u32 r = (u + 0x7fffu + ((u >> 16) & 1u)) >> 16;
    return (u16)r;
}

// async global->LDS DMA, 16 B per lane; lds dst = wave-uniform base + lane*16
#define GLOAD_LDS(g, l)                                                        \
    __builtin_amdgcn_global_load_lds(                                          \
        (const __attribute__((address_space(1))) void*)(g),                    \
        (__attribute__((address_space(3))) void*)(l), 16, 0, 0)

#define SCHED_FENCE() __builtin_amdgcn_sched_barrier(0)

// log2(10000)/512
#define ROPE_LOG2C (13.287712379549449f / 512.0f)

// ================= fused prep kernel =================
__device__ __forceinline__ void cast_body(const float* __restrict__ x,
                                          u16* __restrict__ y, int L, int tid) {
    const int gid = L * 256 + tid;
    float4 v = ((const float4*)x)[gid];
    ushort4 o;
    o.x = f2bf(v.x); o.y = f2bf(v.y); o.z = f2bf(v.z); o.w = f2bf(v.w);
    ((ushort4*)y)[gid] = o;
}

__device__ __forceinline__ void tcast64_body(const float* __restrict__ S,
                                             u16* __restrict__ Dt, int K, int N,
                                             int n0, int k0, int tid,
                                             char* smem) {
    float (*tile)[65] = (float (*)[65])smem;
    const int tx = tid & 15, ty = tid >> 4;
#pragma unroll
    for (int i = 0; i < 4; i++) {
        const int kr = ty + 16 * i;
        const float4 v = *(const float4*)&S[(size_t)(k0 + kr) * N + n0 + tx * 4];
        tile[kr][tx * 4 + 0] = v.x;
        tile[kr][tx * 4 + 1] = v.y;
        tile[kr][tx * 4 + 2] = v.z;
        tile[kr][tx * 4 + 3] = v.w;
    }
    __syncthreads();
#pragma unroll
    for (int i = 0; i < 4; i++) {
        const int nr = ty + 16 * i;
        ushort4 o;
        o.x = f2bf(tile[tx * 4 + 0][nr]);
        o.y = f2bf(tile[tx * 4 + 1][nr]);
        o.z = f2bf(tile[tx * 4 + 2][nr]);
        o.w = f2bf(tile[tx * 4 + 3][nr]);
        *(ushort4*)&Dt[(size_t)(n0 + nr) * K + k0 + tx * 4] = o;
    }
}

// rope role: one block per t. P[t][r] = sum_j base[t][j]*rA[j][r] computed
// in-block (thread owns 4 j's), tree-reduced; then sf/cf elementwise.
__device__ __forceinline__ void ropef_body(const float* __restrict__ rA,
                                           const float* __restrict__ Bw,
                                           float* __restrict__ sf,
                                           float* __restrict__ cf,
                                           int t, int tid, char* smem) {
    float* red = (float*)smem;   // [4][16] wave sums, [64..80) final P
    float p[16];
#pragma unroll
    for (int r = 0; r < 16; ++r) p[r] = 0.f;
#pragma unroll
    for (int jj = 0; jj < 4; ++jj) {
        const int j = tid * 4 + jj;
        const int i = (j < 512) ? j : (j - 512);
        const float th = exp2f(-(float)i * ROPE_LOG2C);
        const float ang = (float)t * th;
        const float base = (j < 512) ? sinf(ang) : cosf(ang);
        const float4* arow = (const float4*)&rA[j * 16];
        const float4 a0 = arow[0], a1 = arow[1], a2 = arow[2], a3 = arow[3];
        p[0] = fmaf(base, a0.x, p[0]);  p[1] = fmaf(base, a0.y, p[1]);
        p[2] = fmaf(base, a0.z, p[2]);  p[3] = fmaf(base, a0.w, p[3]);
        p[4] = fmaf(base, a1.x, p[4]);  p[5] = fmaf(base, a1.y, p[5]);
        p[6] = fmaf(base, a1.z, p[6]);  p[7] = fmaf(base, a1.w, p[7]);
        p[8] = fmaf(base, a2.x, p[8]);  p[9] = fmaf(base, a2.y, p[9]);
        p[10] = fmaf(base, a2.z, p[10]); p[11] = fmaf(base, a2.w, p[11]);
        p[12] = fmaf(base, a3.x, p[12]); p[13] = fmaf(base, a3.y, p[13]);
        p[14] = fmaf(base, a3.z, p[14]); p[15] = fmaf(base, a3.w, p[15]);
    }
    const int w = tid >> 6, lane = tid & 63;
#pragma unroll
    for (int r = 0; r < 16; ++r) {
        float v = p[r];
        v += __shfl_xor(v, 1);  v += __shfl_xor(v, 2);
        v += __shfl_xor(v, 4);  v += __shfl_xor(v, 8);
        v += __shfl_xor(v, 16); v += __shfl_xor(v, 32);
        if (lane == 0) red[w * 16 + r] = v;
    }
    __syncthreads();
    if (tid < 16)
        red[64 + tid] = red[tid] + red[16 + tid] + red[32 + tid] + red[48 + tid];
    __syncthreads();
#pragma unroll
    for (int half = 0; half < 2; ++half) {
        const int i = tid + half * 256;
        float ls = 0.f, lc = 0.f;
#pragma unroll
        for (int r = 0; r < 16; ++r) {
            const float Pr = red[64 + r];
            ls = fmaf(Pr, Bw[r * 1024 + i], ls);
            lc = fmaf(Pr, Bw[r * 1024 + 512 + i], lc);
        }
        const float th = exp2f(-(float)i * ROPE_LOG2C);
        const float ang = (float)t * th;
        sf[t * 512 + i] = sinf(ang) + ls;
        cf[t * 512 + i] = cosf(ang) + lc;
    }
}

__global__ __launch_bounds__(256) void prep_k(
    const float* __restrict__ tgt, u16* __restrict__ tgtb,
    const float* __restrict__ Wq, u16* __restrict__ Wqt,
    const float* __restrict__ Wk, u16* __restrict__ Wkt,
    const float* __restrict__ Wv, u16* __restrict__ Wvt,
    const float* __restrict__ Wo, u16* __restrict__ Wot,
    const float* __restrict__ W1, u16* __restrict__ W1t,
    const float* __restrict__ W2, u16* __restrict__ W2t,
    const float* __restrict__ rA, const float* __restrict__ Bw,
    float* __restrict__ sf, float* __restrict__ cf) {
    __shared__ char smem[64 * 65 * 4];
    const int L = blockIdx.x, tid = threadIdx.x;
    if (L < 2048) {                                    // rope (self-contained)
        ropef_body(rA, Bw, sf, cf, L, tid, smem);
    } else if (L < 6144) {                             // cast tgt -> bf16
        cast_body(tgt, tgtb, L - 2048, tid);
    } else if (L < 7168) {                             // 4x 1024^2 transpose
        const int i = L - 6144;
        const int r = i >> 8, j = i & 255;
        const float* S = r == 0 ? Wq : (r == 1 ? Wk : (r == 2 ? Wv : Wo));
        u16* Dt = r == 0 ? Wqt : (r == 1 ? Wkt : (r == 2 ? Wvt : Wot));
        tcast64_body(S, Dt, 1024, 1024, (j & 15) * 64, (j >> 4) * 64, tid, smem);
    } else if (L < 8192) {                             // W1 (1024x4096)
        const int j = L - 7168;
        tcast64_body(W1, W1t, 1024, 4096, (j & 63) * 64, (j >> 6) * 64, tid, smem);
    } else {                                           // W2 (4096x1024)
        const int j = L - 8192;
        tcast64_body(W2, W2t, 4096, 1024, (j & 15) * 64, (j >> 4) * 64, tid, smem);
    }
}

// XCD supertile mapping: linear grid; xcd = L&7 owns an rn x rm tile region.
__device__ __forceinline__ void xcd_tile(int L, int xn, int rn, int rm,
                                         int& tm, int& tn) {
    const int xcd = L & 7, i = L >> 3;
    const int cx = xcd % xn, cy = xcd / xn;
    tn = cx * rn + (i % rn);
    tm = cy * rm + (i / rn);
}

// ---------- MFMA GEMM (128xBN, 4 waves): 3-stage DMA pipeline ----
// Split-K: tm >= mtiles selects K-half kh=1 (A/Bt advance kh*K columns;
// fp32 partial written to Cp2). lda/ldb are full row strides.
enum { EP_NONE = 0, EP_RELU = 3, EP_PART = 4 };

template <int EPI, bool CBF, int BN>
__global__ __launch_bounds__(256) void mgemm_k(
    const u16* __restrict__ A, const u16* __restrict__ Bt,
    const float* __restrict__ bias, void* __restrict__ Cp,
    void* __restrict__ Cp2, int M, int N, int K, int lda, int ldb,
    int xn, int rn, int rm, int mtiles) {
    constexpr int NT = BN / 32;            // n-frags per wave
    __shared__ u16 As[3 * 128 * 32];
    __shared__ u16 Bs[3 * BN * 32];
    const int tid = threadIdx.x;
    const int w = tid >> 6, l = tid & 63;
    const int quad = l >> 4, lr = l & 15;
    const int wr = w >> 1, wc = w & 1;
    int tm, tn;
    xcd_tile(blockIdx.x, xn, rn, rm, tm, tn);
    int kh = 0;
    if (tm >= mtiles) { kh = 1; tm -= mtiles; }
    const u16* Ak = A + (size_t)kh * K;
    const u16* Bk = Bt + (size_t)kh * K;
    void* Co = kh ? Cp2 : Cp;
    const int m0 = tm * 128, n0 = tn * BN;

    const int srow = w * 16 + (l >> 2);    // staging row (64-row round)
    const int scol = (((l & 3) ^ ((l >> 3) & 3)) * 8);
    const u16* ag0 = Ak + (size_t)(m0 + srow) * lda + scol;
    const u16* ag1 = Ak + (size_t)(m0 + 64 + srow) * lda + scol;
    const u16* bg0 = Bk + (size_t)(n0 + srow) * ldb + scol;
    const u16* bg1 = Bk + (size_t)(n0 + 64 + srow) * ldb + scol;  // BN==128 only

    f32x4 acc[4][NT];
#pragma unroll
    for (int i = 0; i < 4; i++)
#pragma unroll
        for (int j = 0; j < NT; j++) acc[i][j] = (f32x4)(0.0f);

    // prologue: stage tiles 0,1 into buffers 0,1 (issue order = tile order)
    {
        GLOAD_LDS(ag0, As + w * 512);
        GLOAD_LDS(ag1, As + 2048 + w * 512);
        GLOAD_LDS(bg0, Bs + w * 512);
        if (BN == 128) GLOAD_LDS(bg1, Bs + 2048 + w * 512);
        GLOAD_LDS(ag0 + 32, As + 4096 + w * 512);
        GLOAD_LDS(ag1 + 32, As + 4096 + 2048 + w * 512);
        GLOAD_LDS(bg0 + 32, Bs + BN * 32 + w * 512);
        if (BN == 128) GLOAD_LDS(bg1 + 32, Bs + BN * 32 + 2048 + w * 512);
    }

    const int niter = K >> 5;
    const int xsw = ((lr >> 1) & 3) << 3;  // read-side granule XOR (u16 units)
    int bc = 0, bs = 2;                    // compute buf, stage buf (i+2)%3
    for (int i = 0; i < niter; ++i) {
        SCHED_FENCE();
        if (i + 1 < niter) {
            if (BN == 128) asm volatile("s_waitcnt vmcnt(4) lgkmcnt(0)" ::: "memory");
            else           asm volatile("s_waitcnt vmcnt(3) lgkmcnt(0)" ::: "memory");
        } else {
            asm volatile("s_waitcnt vmcnt(0) lgkmcnt(0)" ::: "memory");
        }
        __builtin_amdgcn_s_barrier();
        SCHED_FENCE();
        if (i + 2 < niter) {
            const int kk = (i + 2) << 5;
            u16* Ab = As + bs * 4096;
            u16* Bb = Bs + bs * (BN * 32);
            GLOAD_LDS(ag0 + kk, Ab + w * 512);
            GLOAD_LDS(ag1 + kk, Ab + 2048 + w * 512);
            GLOAD_LDS(bg0 + kk, Bb + w * 512);
            if (BN == 128) GLOAD_LDS(bg1 + kk, Bb + 2048 + w * 512);
        }
        const u16* Ac = As + bc * 4096;
        const u16* Bc = Bs + bc * (BN * 32);
        short8v af[4], bf[NT];
#pragma unroll
        for (int mt = 0; mt < 4; ++mt)
            af[mt] = *(const short8v*)&Ac[(wr * 64 + mt * 16 + lr) * 32 +
                                          ((quad << 3) ^ xsw)];
#pragma unroll
        for (int nt = 0; nt < NT; ++nt)
            bf[nt] = *(const short8v*)&Bc[(wc * (BN / 2) + nt * 16 + lr) * 32 +
                                          ((quad << 3) ^ xsw)];
#pragma unroll
        for (int mt = 0; mt < 4; ++mt)
#pragma unroll
            for (int nt = 0; nt < NT; ++nt)
                acc[mt][nt] = __builtin_amdgcn_mfma_f32_16x16x32_bf16(
                    af[mt], bf[nt], acc[mt][nt], 0, 0, 0);
        bc = (bc == 2) ? 0 : bc + 1;
        bs = (bs == 2) ? 0 : bs + 1;
    }

#pragma unroll
    for (int mt = 0; mt < 4; ++mt) {
#pragma unroll
        for (int nt = 0; nt < NT; ++nt) {
            const int n = n0 + wc * (BN / 2) + nt * 16 + lr;
            const float bb = (EPI == EP_PART) ? 0.0f : bias[n];
#pragma unroll
            for (int reg = 0; reg < 4; ++reg) {
                const int m = m0 + wr * 64 + mt * 16 + quad * 4 + reg;
                float v = acc[mt][nt][reg] + bb;
                if (EPI == EP_RELU) v = fmaxf(v, 0.f);
                if (CBF) ((u16*)Co)[(size_t)m * N + n] = f2bf(v);
                else     ((float*)Co)[(size_t)m * N + n] = v;
            }
        }
    }
}

// ---------- merged QKV GEMM (N=3072), BN=128, 3-stage pipeline, RoPE ----
// V band (which==2): acc tile staged in LDS (reusing dead As/Bs) then
// copied to Vt with full 128 B contiguous per-thread stores (no RMW).
__global__ __launch_bounds__(256) void mqkv_k(
    const u16* __restrict__ A, const u16* __restrict__ Bt,
    const float* __restrict__ bq, const float* __restrict__ bk,
    const float* __restrict__ bv, const float* __restrict__ sf,
    const float* __restrict__ cf, u16* __restrict__ out,
    u16* __restrict__ Vt) {
    const int K = 1024;
    __shared__ u16 SH[2][3 * 128 * 32];   // [0]=As, [1]=Bs; reused as V stage
    u16* const As = SH[0];
    u16* const Bs = SH[1];
    const int tid = threadIdx.x;
    const int w = tid >> 6, l = tid & 63;
    const int quad = l >> 4, lr = l & 15;
    const int wr = w >> 1, wc = w & 1;
    int tm, tn;
    xcd_tile(blockIdx.x, 4, 6, 16, tm, tn);   // 24n x 32m grid
    const int m0 = tm * 128, n0 = tn * 128;

    const int srow = w * 16 + (l >> 2);
    const int scol = (((l & 3) ^ ((l >> 3) & 3)) * 8);
    const u16* ag0 = A + (size_t)(m0 + srow) * K + scol;
    const u16* ag1 = A + (size_t)(m0 + 64 + srow) * K + scol;
    const u16* bg0 = Bt + (size_t)(n0 + srow) * K + scol;
    const u16* bg1 = Bt + (size_t)(n0 + 64 + srow) * K + scol;

    f32x4 acc[4][4];
#pragma unroll
    for (int i = 0; i < 4; i++)
#pragma unroll
        for (int j = 0; j < 4; j++) acc[i][j] = (f32x4)(0.0f);

    {
        GLOAD_LDS(ag0, As + w * 512);
        GLOAD_LDS(ag1, As + 2048 + w * 512);
        GLOAD_LDS(bg0, Bs + w * 512);
        GLOAD_LDS(bg1, Bs + 2048 + w * 512);
        GLOAD_LDS(ag0 + 32, As + 4096 + w * 512);
        GLOAD_LDS(ag1 + 32, As + 4096 + 2048 + w * 512);
        GLOAD_LDS(bg0 + 32, Bs + 4096 + w * 512);
        GLOAD_LDS(bg1 + 32, Bs + 4096 + 2048 + w * 512);
    }
    const int xsw = ((lr >> 1) & 3) << 3;
    int bc = 0, bsb = 2;
    for (int i = 0; i < 32; ++i) {
        SCHED_FENCE();
        if (i + 1 < 32) {
            asm volatile("s_waitcnt vmcnt(4) lgkmcnt(0)" ::: "memory");
        } else {
            asm volatile("s_waitcnt vmcnt(0) lgkmcnt(0)" ::: "memory");
        }
        __builtin_amdgcn_s_barrier();
        SCHED_FENCE();
        if (i + 2 < 32) {
            const int kk = (i + 2) << 5;
            u16* Ab = As + bsb * 4096;
            u16* Bb = Bs + bsb * 4096;
            GLOAD_LDS(ag0 + kk, Ab + w * 512);
            GLOAD_LDS(ag1 + kk, Ab + 2048 + w * 512);
            GLOAD_LDS(bg0 + kk, Bb + w * 512);
            GLOAD_LDS(bg1 + kk, Bb + 2048 + w * 512);
        }
        const u16* Ac = As + bc * 4096;
        const u16* Bc = Bs + bc * 4096;
        short8v af[4], bf[4];
#pragma unroll
        for (int mt = 0; mt < 4; ++mt)
            af[mt] = *(const short8v*)&Ac[(wr * 64 + mt * 16 + lr) * 32 +
                                          ((quad << 3) ^ xsw)];
#pragma unroll
        for (int nt = 0; nt < 4; ++nt)
            bf[nt] = *(const short8v*)&Bc[(wc * 64 + nt * 16 + lr) * 32 +
                                          ((quad << 3) ^ xsw)];
#pragma unroll
        for (int mt = 0; mt < 4; ++mt)
#pragma unroll
            for (int nt = 0; nt < 4; ++nt)
                acc[mt][nt] = __builtin_amdgcn_mfma_f32_16x16x32_bf16(
                    af[mt], bf[nt], acc[mt][nt], 0, 0, 0);
        bc = (bc == 2) ? 0 : bc + 1;
        bsb = (bsb == 2) ? 0 : bsb + 1;
    }

    const int which = n0 >> 10;  // block-uniform (1024-boundaries align)
    const float* bias = which == 0 ? bq : (which == 1 ? bk : bv);
    u16* Cp = out + (size_t)which * 4096 * 1024;

    if (which == 2) {
        // ---- V band: LDS-staged transpose -> coalesced full-line stores ----
        u16 (*stage)[136] = (u16 (*)[136])&SH[0][0];  // 128 x 136 = 34 KB
        __syncthreads();   // seal: all waves done reading As/Bs
#pragma unroll
        for (int mt = 0; mt < 4; ++mt) {
#pragma unroll
            for (int nt = 0; nt < 4; ++nt) {
                const int colp = wc * 64 + nt * 16 + lr;       // 0..127
                const float bb = bias[(n0 & 1023) + colp];
                const int keyp = wr * 64 + mt * 16 + quad * 4; // 0..124, 8B-al
                ushort4 o;
                o.x = f2bf(acc[mt][nt][0] + bb);
                o.y = f2bf(acc[mt][nt][1] + bb);
                o.z = f2bf(acc[mt][nt][2] + bb);
                o.w = f2bf(acc[mt][nt][3] + bb);
                *(ushort4*)&stage[colp][keyp] = o;
            }
        }
        __syncthreads();
        // copy out: thread owns row = tid>>1, half = tid&1 -> 8 x 16 B
        const int row = tid >> 1;                 // block-local col 0..127
        const int col = (n0 & 1023) + row;
        const int hh = col >> 6, d = col & 63;
        const int b = m0 >> 11;
        const int keybase = m0 & 2047;
        u16* dst = &Vt[((size_t)(b * 16 + hh) * 64 + d) * 2048];
#pragma unroll
        for (int it = 0; it < 8; ++it) {
            const int chunk = (tid & 1) * 8 + it; // 0..15, 8 keys each
            const int key = keybase + chunk * 8;  // key&7 == 0
            const int ksw = (key & ~63) |
                            ((((key >> 3) & 7) ^ (d & 7)) << 3);
            *(ulonglong2*)&dst[ksw] =
                *(const ulonglong2*)&stage[row][chunk * 8];
        }
    } else {
#pragma unroll
        for (int mt = 0; mt < 4; ++mt) {
#pragma unroll
            for (int nt = 0; nt < 4; ++nt) {
                const int n = n0 + wc * 64 + nt * 16 + lr;
                const int col = n & 1023;
                const float bb = bias[col];
#pragma unroll
                for (int reg = 0; reg < 4; ++reg) {
                    const int m = m0 + wr * 64 + mt * 16 + quad * 4 + reg;
                    float v = acc[mt][nt][reg] + bb;
                    const float partner = __shfl_xor(v, 1);
                    const int t = m & 2047;
                    const int fi = col >> 1;
                    const float svv = sf[t * 512 + fi];
                    const float cvv = cf[t * 512 + fi];
                    v = (col & 1) ? fmaf(partner, svv, v * cvv)
                                  : fmaf(v, cvv, -partner * svv);
                    if (which == 0) v *= 0.125f;
                    const int colw = (col & ~63) |
                                     ((((col >> 3) & 7) ^ (m & 7)) << 3) |
                                     (col & 7);
                    Cp[(size_t)m * 1024 + colw] = f2bf(v);
                }
            }
        }
    }
}

// ---------- MFMA flash attention v2 ----------
// 512 blocks, 4 waves, 128 q-rows/block (32/wave), KVBLK=64 double-buffered.
__global__ __launch_bounds__(256, 3) void mattn_k(
    const u16* __restrict__ Q, const u16* __restrict__ Kg,
    const u16* __restrict__ Vt, u16* __restrict__ O) {
    __shared__ u16 QPs[128 * 64];     // Q staging (prologue), then P tiles
    __shared__ u16 Ks[2][64 * 64];
    __shared__ u16 Vs[2][64 * 64];
    const int tid = threadIdx.x;
    const int w = tid >> 6, l = tid & 63;
    const int quad = l >> 4, lr = l & 15;
    const int L = blockIdx.x;                      // 512 blocks
    const int bh = (L & 7) * 4 + ((L >> 3) & 3);   // 4 bh per XCD (L2 locality)
    const int b = bh >> 4, h = bh & 15;
    const int row0 = (L >> 5) * 128;
    const size_t base = (size_t)b * 2048 * 1024 + (size_t)h * 64;
    const size_t vbase = (size_t)bh * 64 * 2048;

    const int dr = l >> 3;
    const int dc = (l & 7) * 8;
    const int g0 = w * 2, g1 = g0 + 1;
    const u16* kg0 = Kg + base + (size_t)(g0 * 8 + dr) * 1024 + dc;
    const u16* kg1 = Kg + base + (size_t)(g1 * 8 + dr) * 1024 + dc;
    const u16* vg0 = Vt + vbase + (size_t)(g0 * 8 + dr) * 2048 + dc;
    const u16* vg1 = Vt + vbase + (size_t)(g1 * 8 + dr) * 2048 + dc;

#pragma unroll
    for (int j = 0; j < 4; ++j) {
        const int g = w * 4 + j;
        GLOAD_LDS(Q + base + (size_t)(row0 + g * 8 + dr) * 1024 + dc,
                  QPs + g * 512);
    }
    GLOAD_LDS(kg0, Ks[0] + g0 * 512);
    GLOAD_LDS(kg1, Ks[0] + g1 * 512);
    GLOAD_LDS(vg0, Vs[0] + g0 * 512);
    GLOAD_LDS(vg1, Vs[0] + g1 * 512);
    __syncthreads();

    const int rsw = lr & 7;
    short8v qf[2][2];
#pragma unroll
    for (int ntq = 0; ntq < 2; ++ntq) {
        const int qr = w * 32 + ntq * 16 + lr;
#pragma unroll
        for (int kh = 0; kh < 2; ++kh)
            qf[ntq][kh] = *(const short8v*)&QPs[qr * 64 +
                (((kh * 4 + quad) ^ rsw) << 3)];
    }

    f32x4 o_acc[2][4];
#pragma unroll
    for (int i = 0; i < 2; ++i)
#pragma unroll
        for (int j = 0; j < 4; ++j) o_acc[i][j] = (f32x4)(0.0f);
    float lsum[2] = {0.f, 0.f};

    for (int i = 0; i < 32; ++i) {
        __syncthreads();
        if (i + 1 < 32) {
            const size_t kro = (size_t)((i + 1) << 6) * 1024;
            const int kco = (i + 1) << 6;
            u16* Kb = Ks[(i + 1) & 1];
            u16* Vb = Vs[(i + 1) & 1];
            GLOAD_LDS(kg0 + kro, Kb + g0 * 512);
            GLOAD_LDS(kg1 + kro, Kb + g1 * 512);
            GLOAD_LDS(vg0 + kco, Vb + g0 * 512);
            GLOAD_LDS(vg1 + kco, Vb + g1 * 512);
        }
        const u16* Kc = Ks[i & 1];
        const u16* Vc = Vs[i & 1];

        f32x4 s[4][2];
#pragma unroll
        for (int mt = 0; mt < 4; ++mt)
#pragma unroll
            for (int ntq = 0; ntq < 2; ++ntq) s[mt][ntq] = (f32x4)(0.0f);
#pragma unroll
        for (int mt = 0; mt < 4; ++mt) {
            const int kr = mt * 16 + lr;
            const short8v kf0 = *(const short8v*)&Kc[kr * 64 + ((quad ^ rsw) << 3)];
            const short8v kf1 = *(const short8v*)&Kc[kr * 64 + (((quad + 4) ^ rsw) << 3)];
#pragma unroll
            for (int ntq = 0; ntq < 2; ++ntq) {
                s[mt][ntq] = __builtin_amdgcn_mfma_f32_16x16x32_bf16(
                    kf0, qf[ntq][0], s[mt][ntq], 0, 0, 0);
                s[mt][ntq] = __builtin_amdgcn_mfma_f32_16x16x32_bf16(
                    kf1, qf[ntq][1], s[mt][ntq], 0, 0, 0);
            }
        }

#pragma unroll
        for (int ntq = 0; ntq < 2; ++ntq) {
            const int prow = w * 32 + ntq * 16 + lr;
#pragma unroll
            for (int mt = 0; mt < 4; ++mt) {
                const float e0 = __expf(s[mt][ntq][0]);
                const float e1 = __expf(s[mt][ntq][1]);
                const float e2 = __expf(s[mt][ntq][2]);
                const float e3 = __expf(s[mt][ntq][3]);
                lsum[ntq] += (e0 + e1) + (e2 + e3);
                u32 p01, p23;
                asm("v_cvt_pk_bf16_f32 %0, %1, %2" : "=v"(p01) : "v"(e0), "v"(e1));
                asm("v_cvt_pk_bf16_f32 %0, %1, %2" : "=v"(p23) : "v"(e2), "v"(e3));
                uint2 pv; pv.x = p01; pv.y = p23;
                *(uint2*)&QPs[prow * 64 +
                              (((mt * 2 + (quad >> 1)) ^ rsw) << 3) +
                              (quad & 1) * 4] = pv;
            }
        }

        short8v vf[4][2];
#pragma unroll
        for (int ntd = 0; ntd < 4; ++ntd) {
            const int vr = ntd * 16 + lr;
            vf[ntd][0] = *(const short8v*)&Vc[vr * 64 + ((quad ^ rsw) << 3)];
            vf[ntd][1] = *(const short8v*)&Vc[vr * 64 + (((quad + 4) ^ rsw) << 3)];
        }
        short8v pf[2][2];
#pragma unroll
        for (int mtq = 0; mtq < 2; ++mtq) {
            const int prow = w * 32 + mtq * 16 + lr;
            pf[mtq][0] = *(const short8v*)&QPs[prow * 64 + ((quad ^ rsw) << 3)];
            pf[mtq][1] = *(const short8v*)&QPs[prow * 64 + (((quad + 4) ^ rsw) << 3)];
        }
#pragma unroll
        for (int mtq = 0; mtq < 2; ++mtq)
#pragma unroll
            for (int ntd = 0; ntd < 4; ++ntd) {
                o_acc[mtq][ntd] = __builtin_amdgcn_mfma_f32_16x16x32_bf16(
                    pf[mtq][0], vf[ntd][0], o_acc[mtq][ntd], 0, 0, 0);
                o_acc[mtq][ntd] = __builtin_amdgcn_mfma_f32_16x16x32_bf16(
                    pf[mtq][1], vf[ntd][1], o_acc[mtq][ntd], 0, 0, 0);
            }
    }

    float rden[2];
#pragma unroll
    for (int ntq = 0; ntq < 2; ++ntq) {
        float t = lsum[ntq];
        t += __shfl_xor(t, 16);
        t += __shfl_xor(t, 32);
        rden[ntq] = 1.0f / t;
    }
#pragma unroll
    for (int mtq = 0; mtq < 2; ++mtq) {
#pragma unroll
        for (int reg = 0; reg < 4; ++reg) {
            const float dsc = __shfl(rden[mtq], quad * 4 + reg);
            const int m = row0 + w * 32 + mtq * 16 + quad * 4 + reg;
#pragma unroll
            for (int ntd = 0; ntd < 4; ++ntd)
                O[base + (size_t)m * 1024 + ntd * 16 + lr] =
                    f2bf(o_acc[mtq][ntd][reg] * dsc);
        }
    }
}

// ---------- fused partial-sum + bias + layernorm over 1024 cols ----------
__global__ __launch_bounds__(256) void lnf_k(
    const float* __restrict__ X, const float* __restrict__ P0,
    const float* __restrict__ P1, const float* __restrict__ cb,
    const float* __restrict__ g, const float* __restrict__ bb,
    float* __restrict__ outf, u16* __restrict__ outb) {
    const int row = blockIdx.x, tid = threadIdx.x;
    const size_t off = (size_t)row * 1024 + tid * 4;
    float4 xv = *(const float4*)&X[off];
    float4 p0 = *(const float4*)&P0[off];
    float4 p1 = *(const float4*)&P1[off];
    float4 c4 = *(const float4*)&cb[tid * 4];
    xv.x += p0.x + p1.x + c4.x;
    xv.y += p0.y + p1.y + c4.y;
    xv.z += p0.z + p1.z + c4.z;
    xv.w += p0.w + p1.w + c4.w;
    float s = xv.x + xv.y + xv.z + xv.w;
    float s2 = xv.x * xv.x + xv.y * xv.y + xv.z * xv.z + xv.w * xv.w;
#pragma unroll
    for (int msk = 32; msk >= 1; msk >>= 1) {
        s += __shfl_xor(s, msk);
        s2 += __shfl_xor(s2, msk);
    }
    __shared__ float red[8];
    const int wv = tid >> 6;
    if ((tid & 63) == 0) { red[wv] = s; red[wv + 4] = s2; }
    __syncthreads();
    s = red[0] + red[1] + red[2] + red[3];
    s2 = red[4] + red[5] + red[6] + red[7];
    const float mu = s * (1.f / 1024.f);
    float var = s2 * (1.f / 1024.f) - mu * mu;
    var = fmaxf(var, 0.f);
    const float rstd = rsqrtf(var + 1e-5f);
    float4 g4 = *(const float4*)&g[tid * 4];
    float4 b4 = *(const float4*)&bb[tid * 4];
    float o0 = (xv.x - mu) * rstd * g4.x + b4.x;
    float o1 = (xv.y - mu) * rstd * g4.y + b4.y;
    float o2 = (xv.z - mu) * rstd * g4.z + b4.z;
    float o3 = (xv.w - mu) * rstd * g4.w + b4.w;
    if (outf)
        *(float4*)(outf + off) = make_float4(o0, o1, o2, o3);
    if (outb) {
        ushort4 ov;
        ov.x = f2bf(o0); ov.y = f2bf(o1); ov.z = f2bf(o2); ov.w = f2bf(o3);
        *(ushort4*)(outb + off) = ov;
    }
}

extern "C" void kernel_launch(void* const* d_in, const int* in_sizes, int n_in,
                              void* d_out, int out_size, void* d_ws, size_t ws_size,
                              hipStream_t stream) {
    const float* tgt = (const float*)d_in[0];
    const float* Wq  = (const float*)d_in[1];
    const float* bq  = (const float*)d_in[2];
    const float* Wk  = (const float*)d_in[3];
    const float* bk  = (const float*)d_in[4];
    const float* Wv  = (const float*)d_in[5];
    const float* bv  = (const float*)d_in[6];
    const float* Wo  = (const float*)d_in[7];
    const float* bo  = (const float*)d_in[8];
    const float* W1  = (const float*)d_in[9];
    const float* b1  = (const float*)d_in[10];
    const float* W2  = (const float*)d_in[11];
    const float* b2  = (const float*)d_in[12];
    const float* g1  = (const float*)d_in[13];
    const float* be1 = (const float*)d_in[14];
    const float* g2  = (const float*)d_in[15];
    const float* be2 = (const float*)d_in[16];
    const float* rA  = (const float*)d_in[17];
    const float* rB  = (const float*)d_in[18];

    const int M = 4096, D = 1024, DFF = 4096;
    const size_t MD = (size_t)M * D;
    const size_t MB = 1u << 20;
    char* wsb = (char*)d_ws;

    // Lifetime-aliased layout (88 MB total); vv eliminated (V goes straight
    // to Vt from mqkv).
    u16* q    = (u16*)wsb;
    u16* ctx  = (u16*)(wsb + 16 * MB);
    u16* Vt   = (u16*)(wsb + 24 * MB);
    u16* h    = q;
    float* PW0 = (float*)wsb;
    float* PW1 = (float*)(wsb + 32 * MB);
    float* PF0 = (float*)(wsb + 64 * MB);
    float* PF1 = (float*)(wsb + 32 * MB);
    float* sfp = (float*)(wsb + 32 * MB);
    float* cfp = sfp + (size_t)2048 * 512;
    u16* tgtb = (u16*)(wsb + 40 * MB);
    float* x1  = (float*)(wsb + 48 * MB);
    u16* x1b  = (u16*)(wsb + 64 * MB);
    u16* Wqt  = (u16*)(wsb + 64 * MB);
    u16* Wkt  = (u16*)(wsb + 66 * MB);
    u16* Wvt  = (u16*)(wsb + 68 * MB);
    u16* Wot  = (u16*)(wsb + 70 * MB);
    u16* W1t  = (u16*)(wsb + 72 * MB);
    u16* W2t  = (u16*)(wsb + 80 * MB);

    // fused prep: rope (self-contained P) + cast + 6 weight transposes
    prep_k<<<dim3(9216), dim3(256), 0, stream>>>(
        tgt, tgtb, Wq, Wqt, Wk, Wkt, Wv, Wvt, Wo, Wot,
        W1, W1t, W2, W2t, rA, rB, sfp, cfp);

    // QKV BN=128: 24n x 32m = 768 blocks (3/CU); V written directly to Vt
    mqkv_k<<<dim3(768), dim3(256), 0, stream>>>(
        tgtb, Wqt, bq, bk, bv, sfp, cfp, q, Vt);

    // 512 blocks: 8 xcd x 4 bh x 16 row-tiles (128 q rows each)
    mattn_k<<<dim3(512), dim3(256), 0, stream>>>(q, q + MD, Vt, ctx);

    // Wo split-K x2, BN=128 (R6 best): 8n x (32m x 2kh) = 512 blocks, K=512
    mgemm_k<EP_PART, false, 128><<<dim3(512), dim3(256), 0, stream>>>(
        ctx, Wot, nullptr, PW0, PW1, M, D, 512, D, D, 1, 8, 8, 32);
    // lnf1: x_attn = tgt + PW0 + PW1 + bo -> LN -> x1 (fp32) + x1b (bf16)
    lnf_k<<<dim3(4096), dim3(256), 0, stream>>>(
        tgt, PW0, PW1, bo, g1, be1, x1, x1b);
    // FFN1: BN=128 -> 32n x 32m = 1024 blocks; xn=4 -> 8n x 16m per XCD
    mgemm_k<EP_RELU, true, 128><<<dim3(1024), dim3(256), 0, stream>>>(
        x1b, W1t, b1, h, nullptr, M, DFF, D, D, D, 4, 8, 16, 1 << 20);
    // FFN2 split-K x2, BN=64 (R8 best): 16n x (32m x 2kh) = 1024 blocks, K=2048
    mgemm_k<EP_PART, false, 64><<<dim3(1024), dim3(256), 0, stream>>>(
        h, W2t, nullptr, PF0, PF1, M, D, 2048, DFF, DFF, 2, 8, 16, 32);
    // lnf2: x_out = ln2(x1 + PF0 + PF1 + b2) -> d_out
    lnf_k<<<dim3(4096), dim3(256), 0, stream>>>(
        x1, PF0, PF1, b2, g2, be2, (float*)d_out, nullptr);

    (void)in_sizes; (void)n_in; (void)out_size; (void)ws_size;
}